// Round 1
// baseline (1919.510 us; speedup 1.0000x reference)
//
#include <hip/hip_runtime.h>

constexpr int HID = 128;

// ---------------------------------------------------------------------------
// Scatter-add aggregation: agg[dst[e]] += feat[src[e]]  (one wave per edge)
// Each lane handles 2 consecutive floats (float2) -> 512B coalesced row read.
// ---------------------------------------------------------------------------
__global__ __launch_bounds__(256) void scatter_add_k(
    const float* __restrict__ feat,
    const int*   __restrict__ src,
    const int*   __restrict__ dst,
    float*       __restrict__ agg,
    int nEdges)
{
    const int w = (int)((blockIdx.x * blockDim.x + threadIdx.x) >> 6);
    if (w >= nEdges) return;
    const int lane = threadIdx.x & 63;
    const int s = src[w];
    const int d = dst[w];
    const float2 v = *reinterpret_cast<const float2*>(feat + (size_t)s * HID + lane * 2);
    float* o = agg + (size_t)d * HID + lane * 2;
    unsafeAtomicAdd(o + 0, v.x);
    unsafeAtomicAdd(o + 1, v.y);
}

// ---------------------------------------------------------------------------
// Fused dual GEMM: OUT[r,:] = act( X[r,:]@Wroot^T + AGG[r,:]@Wrel^T + bias )
// 64-row tile per block, full 128 cols, K=256 (concat) in 4 chunks of 64.
// 256 threads: thread -> (rgrp=tid>>5 : 8 rows, cgrp=tid&31 : 4 cols), acc[8][4].
// ---------------------------------------------------------------------------
template <bool RELU>
__global__ __launch_bounds__(256) void gconv_gemm_k(
    const float* __restrict__ X,
    const float* __restrict__ AGG,
    const float* __restrict__ Wroot,
    const float* __restrict__ Wrel,
    const float* __restrict__ bias,
    float*       __restrict__ OUT,
    int nRows)
{
    __shared__ float Xs[64][68];    // 17.4 KB (pad 68 breaks staging bank conflict)
    __shared__ float Ws[64][128];   // 32 KB, W^T chunk: Ws[k][c]

    const int tid  = threadIdx.x;
    const int row0 = blockIdx.x * 64;
    const int rgrp = tid >> 5;   // 0..7
    const int cgrp = tid & 31;   // 0..31

    float acc[8][4];
#pragma unroll
    for (int i = 0; i < 8; ++i)
#pragma unroll
        for (int j = 0; j < 4; ++j) acc[i][j] = 0.f;

#pragma unroll
    for (int chunk = 0; chunk < 4; ++chunk) {
        const float* F = (chunk < 2) ? X : AGG;
        const float* W = (chunk < 2) ? Wroot : Wrel;
        const int k0 = (chunk & 1) * 64;

        // --- stage X chunk: Xs[r][k] = F[row0+r][k0+k], 16 floats per thread
        {
            const int r  = tid >> 2;
            const int kk = (tid & 3) * 16;
            const int gr = row0 + r;
            float4 v0 = make_float4(0.f, 0.f, 0.f, 0.f);
            float4 v1 = v0, v2 = v0, v3 = v0;
            if (gr < nRows) {
                const float* p = F + (size_t)gr * HID + k0 + kk;
                v0 = *reinterpret_cast<const float4*>(p + 0);
                v1 = *reinterpret_cast<const float4*>(p + 4);
                v2 = *reinterpret_cast<const float4*>(p + 8);
                v3 = *reinterpret_cast<const float4*>(p + 12);
            }
            *reinterpret_cast<float4*>(&Xs[r][kk + 0])  = v0;
            *reinterpret_cast<float4*>(&Xs[r][kk + 4])  = v1;
            *reinterpret_cast<float4*>(&Xs[r][kk + 8])  = v2;
            *reinterpret_cast<float4*>(&Xs[r][kk + 12]) = v3;
        }
        // --- stage W^T chunk: Ws[k][c] = W[c][k0+k], 32 floats per thread
        {
            const int c  = tid >> 1;
            const int kh = (tid & 1) * 32;
            const float* p = W + c * HID + k0 + kh;
#pragma unroll
            for (int j = 0; j < 32; j += 4) {
                const float4 wv = *reinterpret_cast<const float4*>(p + j);
                Ws[kh + j + 0][c] = wv.x;
                Ws[kh + j + 1][c] = wv.y;
                Ws[kh + j + 2][c] = wv.z;
                Ws[kh + j + 3][c] = wv.w;
            }
        }
        __syncthreads();

#pragma unroll 8
        for (int k = 0; k < 64; ++k) {
            const float4 wv = *reinterpret_cast<const float4*>(&Ws[k][cgrp * 4]);
#pragma unroll
            for (int ri = 0; ri < 8; ++ri) {
                const float xv = Xs[rgrp * 8 + ri][k];
                acc[ri][0] = fmaf(xv, wv.x, acc[ri][0]);
                acc[ri][1] = fmaf(xv, wv.y, acc[ri][1]);
                acc[ri][2] = fmaf(xv, wv.z, acc[ri][2]);
                acc[ri][3] = fmaf(xv, wv.w, acc[ri][3]);
            }
        }
        __syncthreads();
    }

    const float4 bv = *reinterpret_cast<const float4*>(&bias[cgrp * 4]);
#pragma unroll
    for (int ri = 0; ri < 8; ++ri) {
        const int r = row0 + rgrp * 8 + ri;
        if (r < nRows) {
            float4 o;
            o.x = acc[ri][0] + bv.x;
            o.y = acc[ri][1] + bv.y;
            o.z = acc[ri][2] + bv.z;
            o.w = acc[ri][3] + bv.w;
            if (RELU) {
                o.x = fmaxf(o.x, 0.f);
                o.y = fmaxf(o.y, 0.f);
                o.z = fmaxf(o.z, 0.f);
                o.w = fmaxf(o.w, 0.f);
            }
            *reinterpret_cast<float4*>(OUT + (size_t)r * HID + cgrp * 4) = o;
        }
    }
}

extern "C" void kernel_launch(void* const* d_in, const int* in_sizes, int n_in,
                              void* d_out, int out_size, void* d_ws, size_t ws_size,
                              hipStream_t stream)
{
    const float* x      = (const float*)d_in[0];
    const int*   ei     = (const int*)  d_in[1];
    const float* Wrel0  = (const float*)d_in[2];
    const float* b0     = (const float*)d_in[3];
    const float* Wroot0 = (const float*)d_in[4];
    const float* Wrel1  = (const float*)d_in[5];
    const float* b1     = (const float*)d_in[6];
    const float* Wroot1 = (const float*)d_in[7];
    const float* Wrel2  = (const float*)d_in[8];
    const float* b2     = (const float*)d_in[9];
    const float* Wroot2 = (const float*)d_in[10];

    const int nNodes = in_sizes[0] / HID;   // 100000
    const int nEdges = in_sizes[1] / 2;     // 640000
    const int* srcI = ei;
    const int* dstI = ei + nEdges;

    float* OUT = (float*)d_out;
    float* A   = (float*)d_ws;                       // h0 (51.2 MB)
    float* C   = A + (size_t)nNodes * HID;           // agg scratch (51.2 MB)

    const size_t featBytes = (size_t)nNodes * HID * sizeof(float);
    const int sGrid = (nEdges + 3) / 4;              // 4 edges (waves) per block
    const int gGrid = (nNodes + 63) / 64;

    // ---- layer 0: h0 = relu(x@Wroot0^T + agg(x)@Wrel0^T + b0) -> A
    hipMemsetAsync(C, 0, featBytes, stream);
    scatter_add_k<<<sGrid, 256, 0, stream>>>(x, srcI, dstI, C, nEdges);
    gconv_gemm_k<true><<<gGrid, 256, 0, stream>>>(x, C, Wroot0, Wrel0, b0, A, nNodes);

    // ---- layer 1: h1 = relu(A@Wroot1^T + agg(A)@Wrel1^T + b1) -> OUT
    hipMemsetAsync(C, 0, featBytes, stream);
    scatter_add_k<<<sGrid, 256, 0, stream>>>(A, srcI, dstI, C, nEdges);
    gconv_gemm_k<true><<<gGrid, 256, 0, stream>>>(A, C, Wroot1, Wrel1, b1, OUT, nNodes);

    // ---- layer 2: out = OUT@Wroot2^T + agg(OUT)@Wrel2^T + b2 (in-place safe)
    hipMemsetAsync(C, 0, featBytes, stream);
    scatter_add_k<<<sGrid, 256, 0, stream>>>(OUT, srcI, dstI, C, nEdges);
    gconv_gemm_k<false><<<gGrid, 256, 0, stream>>>(OUT, C, Wroot2, Wrel2, b2, OUT, nNodes);
}

// Round 2
// 562.142 us; speedup vs baseline: 3.4146x; 3.4146x over previous
//
#include <hip/hip_runtime.h>

constexpr int HID = 128;

// ===========================================================================
// CSR-by-dst construction (once per launch, reused by all 3 layers)
// ===========================================================================
__global__ __launch_bounds__(256) void hist_k(
    const int* __restrict__ dst, int* __restrict__ deg, int nEdges)
{
    const int i = blockIdx.x * blockDim.x + threadIdx.x;
    if (i < nEdges) atomicAdd(&deg[dst[i]], 1);
}

// Per-block (1024 elements) exclusive scan; emits per-block totals.
__global__ __launch_bounds__(256) void scan1_k(
    const int* __restrict__ deg, int* __restrict__ part,
    int* __restrict__ blockSums, int n)
{
    __shared__ int s[256];
    const int t = threadIdx.x;
    const int base = blockIdx.x * 1024;
    const int i = base + t * 4;
    const int e0 = (i + 0 < n) ? deg[i + 0] : 0;
    const int e1 = (i + 1 < n) ? deg[i + 1] : 0;
    const int e2 = (i + 2 < n) ? deg[i + 2] : 0;
    const int e3 = (i + 3 < n) ? deg[i + 3] : 0;
    const int local = e0 + e1 + e2 + e3;
    s[t] = local;
    __syncthreads();
    for (int off = 1; off < 256; off <<= 1) {
        int v = 0;
        if (t >= off) v = s[t - off];
        __syncthreads();
        if (t >= off) s[t] += v;
        __syncthreads();
    }
    const int incl = s[t];
    int excl = incl - local;
    if (t == 255) blockSums[blockIdx.x] = incl;
    if (i + 0 < n) part[i + 0] = excl; excl += e0;
    if (i + 1 < n) part[i + 1] = excl; excl += e1;
    if (i + 2 < n) part[i + 2] = excl; excl += e2;
    if (i + 3 < n) part[i + 3] = excl;
}

// Serial exclusive scan over <=128 block sums (tiny).
__global__ void scan2_k(int* __restrict__ blockSums, int nb)
{
    if (threadIdx.x == 0 && blockIdx.x == 0) {
        int run = 0;
        for (int b = 0; b < nb; ++b) { const int v = blockSums[b]; blockSums[b] = run; run += v; }
    }
}

__global__ __launch_bounds__(256) void scan3_k(
    const int* __restrict__ part, const int* __restrict__ blockSums,
    int* __restrict__ rowStart, int n, int nEdges)
{
    const int i = blockIdx.x * blockDim.x + threadIdx.x;
    if (i < n) rowStart[i] = part[i] + blockSums[i >> 10];
    if (i == n) rowStart[n] = nEdges;
}

__global__ __launch_bounds__(256) void fill_k(
    const int* __restrict__ src, const int* __restrict__ dst,
    int* __restrict__ cursor, int* __restrict__ eSrc, int nEdges)
{
    const int i = blockIdx.x * blockDim.x + threadIdx.x;
    if (i < nEdges) {
        const int pos = atomicAdd(&cursor[dst[i]], 1);
        eSrc[pos] = src[i];
    }
}

// ===========================================================================
// Gather aggregation: agg[i,:] = sum over incoming edges of feat[src,:]
// One wave per dst node; lane covers 2 floats; row written exactly once.
// ===========================================================================
__global__ __launch_bounds__(256) void gather_agg_k(
    const float* __restrict__ feat,
    const int*   __restrict__ rowStart,
    const int*   __restrict__ eSrc,
    float*       __restrict__ agg,
    int nNodes)
{
    const int node = (int)((blockIdx.x * blockDim.x + threadIdx.x) >> 6);
    if (node >= nNodes) return;
    const int lane = threadIdx.x & 63;
    const int beg = rowStart[node];
    const int end = rowStart[node + 1];

    float2 acc = make_float2(0.f, 0.f);
    int e = beg;
    for (; e + 2 <= end; e += 2) {
        const int s0 = eSrc[e];
        const int s1 = eSrc[e + 1];
        const float2 v0 = *reinterpret_cast<const float2*>(feat + (size_t)s0 * HID + lane * 2);
        const float2 v1 = *reinterpret_cast<const float2*>(feat + (size_t)s1 * HID + lane * 2);
        acc.x += v0.x + v1.x;
        acc.y += v0.y + v1.y;
    }
    if (e < end) {
        const int s = eSrc[e];
        const float2 v = *reinterpret_cast<const float2*>(feat + (size_t)s * HID + lane * 2);
        acc.x += v.x;
        acc.y += v.y;
    }
    *reinterpret_cast<float2*>(agg + (size_t)node * HID + lane * 2) = acc;
}

// ===========================================================================
// Fused dual GEMM: OUT[r,:] = act( X[r,:]@Wroot^T + AGG[r,:]@Wrel^T + bias )
// ===========================================================================
template <bool RELU>
__global__ __launch_bounds__(256) void gconv_gemm_k(
    const float* __restrict__ X,
    const float* __restrict__ AGG,
    const float* __restrict__ Wroot,
    const float* __restrict__ Wrel,
    const float* __restrict__ bias,
    float*       __restrict__ OUT,
    int nRows)
{
    __shared__ float Xs[64][68];
    __shared__ float Ws[64][128];

    const int tid  = threadIdx.x;
    const int row0 = blockIdx.x * 64;
    const int rgrp = tid >> 5;
    const int cgrp = tid & 31;

    float acc[8][4];
#pragma unroll
    for (int i = 0; i < 8; ++i)
#pragma unroll
        for (int j = 0; j < 4; ++j) acc[i][j] = 0.f;

#pragma unroll
    for (int chunk = 0; chunk < 4; ++chunk) {
        const float* F = (chunk < 2) ? X : AGG;
        const float* W = (chunk < 2) ? Wroot : Wrel;
        const int k0 = (chunk & 1) * 64;

        {
            const int r  = tid >> 2;
            const int kk = (tid & 3) * 16;
            const int gr = row0 + r;
            float4 v0 = make_float4(0.f, 0.f, 0.f, 0.f);
            float4 v1 = v0, v2 = v0, v3 = v0;
            if (gr < nRows) {
                const float* p = F + (size_t)gr * HID + k0 + kk;
                v0 = *reinterpret_cast<const float4*>(p + 0);
                v1 = *reinterpret_cast<const float4*>(p + 4);
                v2 = *reinterpret_cast<const float4*>(p + 8);
                v3 = *reinterpret_cast<const float4*>(p + 12);
            }
            *reinterpret_cast<float4*>(&Xs[r][kk + 0])  = v0;
            *reinterpret_cast<float4*>(&Xs[r][kk + 4])  = v1;
            *reinterpret_cast<float4*>(&Xs[r][kk + 8])  = v2;
            *reinterpret_cast<float4*>(&Xs[r][kk + 12]) = v3;
        }
        {
            const int c  = tid >> 1;
            const int kh = (tid & 1) * 32;
            const float* p = W + c * HID + k0 + kh;
#pragma unroll
            for (int j = 0; j < 32; j += 4) {
                const float4 wv = *reinterpret_cast<const float4*>(p + j);
                Ws[kh + j + 0][c] = wv.x;
                Ws[kh + j + 1][c] = wv.y;
                Ws[kh + j + 2][c] = wv.z;
                Ws[kh + j + 3][c] = wv.w;
            }
        }
        __syncthreads();

#pragma unroll 8
        for (int k = 0; k < 64; ++k) {
            const float4 wv = *reinterpret_cast<const float4*>(&Ws[k][cgrp * 4]);
#pragma unroll
            for (int ri = 0; ri < 8; ++ri) {
                const float xv = Xs[rgrp * 8 + ri][k];
                acc[ri][0] = fmaf(xv, wv.x, acc[ri][0]);
                acc[ri][1] = fmaf(xv, wv.y, acc[ri][1]);
                acc[ri][2] = fmaf(xv, wv.z, acc[ri][2]);
                acc[ri][3] = fmaf(xv, wv.w, acc[ri][3]);
            }
        }
        __syncthreads();
    }

    const float4 bv = *reinterpret_cast<const float4*>(&bias[cgrp * 4]);
#pragma unroll
    for (int ri = 0; ri < 8; ++ri) {
        const int r = row0 + rgrp * 8 + ri;
        if (r < nRows) {
            float4 o;
            o.x = acc[ri][0] + bv.x;
            o.y = acc[ri][1] + bv.y;
            o.z = acc[ri][2] + bv.z;
            o.w = acc[ri][3] + bv.w;
            if (RELU) {
                o.x = fmaxf(o.x, 0.f);
                o.y = fmaxf(o.y, 0.f);
                o.z = fmaxf(o.z, 0.f);
                o.w = fmaxf(o.w, 0.f);
            }
            *reinterpret_cast<float4*>(OUT + (size_t)r * HID + cgrp * 4) = o;
        }
    }
}

extern "C" void kernel_launch(void* const* d_in, const int* in_sizes, int n_in,
                              void* d_out, int out_size, void* d_ws, size_t ws_size,
                              hipStream_t stream)
{
    const float* x      = (const float*)d_in[0];
    const int*   ei     = (const int*)  d_in[1];
    const float* Wrel0  = (const float*)d_in[2];
    const float* b0     = (const float*)d_in[3];
    const float* Wroot0 = (const float*)d_in[4];
    const float* Wrel1  = (const float*)d_in[5];
    const float* b1     = (const float*)d_in[6];
    const float* Wroot1 = (const float*)d_in[7];
    const float* Wrel2  = (const float*)d_in[8];
    const float* b2     = (const float*)d_in[9];
    const float* Wroot2 = (const float*)d_in[10];

    const int nNodes = in_sizes[0] / HID;   // 100000
    const int nEdges = in_sizes[1] / 2;     // 640000
    const int* srcI = ei;
    const int* dstI = ei + nEdges;

    float* OUT = (float*)d_out;

    // ---- workspace layout
    float* A = (float*)d_ws;                         // h0           (51.2 MB)
    float* C = A + (size_t)nNodes * HID;             // agg scratch  (51.2 MB)
    int* deg       = (int*)(C + (size_t)nNodes * HID);
    int* part      = deg + nNodes;
    int* rowStart  = part + nNodes;                  // nNodes+1
    int* cursor    = rowStart + nNodes + 1;
    int* blockSums = cursor + nNodes;                // <=128
    int* eSrc      = blockSums + 128;                // nEdges

    // ---- build CSR by destination (once)
    const int nb = (nNodes + 1023) / 1024;
    hipMemsetAsync(deg, 0, (size_t)nNodes * sizeof(int), stream);
    hist_k<<<(nEdges + 255) / 256, 256, 0, stream>>>(dstI, deg, nEdges);
    scan1_k<<<nb, 256, 0, stream>>>(deg, part, blockSums, nNodes);
    scan2_k<<<1, 64, 0, stream>>>(blockSums, nb);
    scan3_k<<<(nNodes + 256) / 256, 256, 0, stream>>>(part, blockSums, rowStart, nNodes, nEdges);
    hipMemcpyAsync(cursor, rowStart, (size_t)nNodes * sizeof(int),
                   hipMemcpyDeviceToDevice, stream);
    fill_k<<<(nEdges + 255) / 256, 256, 0, stream>>>(srcI, dstI, cursor, eSrc, nEdges);

    const int aGrid = (nNodes * 64 + 255) / 256;     // one wave per node
    const int gGrid = (nNodes + 63) / 64;

    // ---- layer 0: h0 = relu(x@Wroot0^T + agg(x)@Wrel0^T + b0) -> A
    gather_agg_k<<<aGrid, 256, 0, stream>>>(x, rowStart, eSrc, C, nNodes);
    gconv_gemm_k<true><<<gGrid, 256, 0, stream>>>(x, C, Wroot0, Wrel0, b0, A, nNodes);

    // ---- layer 1: h1 = relu(A@Wroot1^T + agg(A)@Wrel1^T + b1) -> OUT
    gather_agg_k<<<aGrid, 256, 0, stream>>>(A, rowStart, eSrc, C, nNodes);
    gconv_gemm_k<true><<<gGrid, 256, 0, stream>>>(A, C, Wroot1, Wrel1, b1, OUT, nNodes);

    // ---- layer 2: out = OUT@Wroot2^T + agg(OUT)@Wrel2^T + b2 (in-place safe)
    gather_agg_k<<<aGrid, 256, 0, stream>>>(OUT, rowStart, eSrc, C, nNodes);
    gconv_gemm_k<false><<<gGrid, 256, 0, stream>>>(OUT, C, Wroot2, Wrel2, b2, OUT, nNodes);
}

// Round 3
// 303.512 us; speedup vs baseline: 6.3243x; 1.8521x over previous
//
#include <hip/hip_runtime.h>

constexpr int HID = 128;

typedef __attribute__((ext_vector_type(8))) short bf16x8;
typedef __attribute__((ext_vector_type(4))) float f32x4;

__device__ __forceinline__ unsigned short f2bf(float f) {
    unsigned int u = __float_as_uint(f);
    u += 0x7fffu + ((u >> 16) & 1u);            // RNE
    return (unsigned short)(u >> 16);
}
__device__ __forceinline__ float bf_lo(unsigned int v) { return __uint_as_float(v << 16); }
__device__ __forceinline__ float bf_hi(unsigned int v) { return __uint_as_float(v & 0xffff0000u); }

__device__ __forceinline__ void gload16(const void* g, void* l) {
    __builtin_amdgcn_global_load_lds(
        (const __attribute__((address_space(1))) void*)g,
        (__attribute__((address_space(3))) void*)l, 16, 0, 0);
}

// ===========================================================================
// f32 -> bf16 conversions
// ===========================================================================
__global__ __launch_bounds__(256) void cvt_x_k(
    const float* __restrict__ in, unsigned short* __restrict__ out, int n4)
{
    const int i = blockIdx.x * 256 + threadIdx.x;
    if (i >= n4) return;
    const float4 v = reinterpret_cast<const float4*>(in)[i];
    ushort4 o;
    o.x = f2bf(v.x); o.y = f2bf(v.y); o.z = f2bf(v.z); o.w = f2bf(v.w);
    reinterpret_cast<ushort4*>(out)[i] = o;
}

struct WPtrs { const float* s[6]; unsigned short* d[6]; };
__global__ __launch_bounds__(256) void cvt_w_k(WPtrs p)
{
    const int which = blockIdx.y;
    const int i = blockIdx.x * 256 + threadIdx.x;
    if (i >= (HID * HID) / 4) return;
    const float4 v = reinterpret_cast<const float4*>(p.s[which])[i];
    ushort4 o;
    o.x = f2bf(v.x); o.y = f2bf(v.y); o.z = f2bf(v.z); o.w = f2bf(v.w);
    reinterpret_cast<ushort4*>(p.d[which])[i] = o;
}

// ===========================================================================
// CSR-by-dst construction (once per launch)
// ===========================================================================
__global__ __launch_bounds__(256) void hist_k(
    const int* __restrict__ dst, int* __restrict__ deg, int nEdges)
{
    const int i = blockIdx.x * blockDim.x + threadIdx.x;
    if (i < nEdges) atomicAdd(&deg[dst[i]], 1);
}

__global__ __launch_bounds__(256) void scan1_k(
    const int* __restrict__ deg, int* __restrict__ part,
    int* __restrict__ blockSums, int n)
{
    __shared__ int s[256];
    const int t = threadIdx.x;
    const int i = blockIdx.x * 1024 + t * 4;
    const int e0 = (i + 0 < n) ? deg[i + 0] : 0;
    const int e1 = (i + 1 < n) ? deg[i + 1] : 0;
    const int e2 = (i + 2 < n) ? deg[i + 2] : 0;
    const int e3 = (i + 3 < n) ? deg[i + 3] : 0;
    const int local = e0 + e1 + e2 + e3;
    s[t] = local;
    __syncthreads();
    for (int off = 1; off < 256; off <<= 1) {
        int v = 0;
        if (t >= off) v = s[t - off];
        __syncthreads();
        if (t >= off) s[t] += v;
        __syncthreads();
    }
    const int incl = s[t];
    int excl = incl - local;
    if (t == 255) blockSums[blockIdx.x] = incl;
    if (i + 0 < n) part[i + 0] = excl; excl += e0;
    if (i + 1 < n) part[i + 1] = excl; excl += e1;
    if (i + 2 < n) part[i + 2] = excl; excl += e2;
    if (i + 3 < n) part[i + 3] = excl;
}

__global__ void scan2_k(int* __restrict__ blockSums, int nb)
{
    if (threadIdx.x == 0 && blockIdx.x == 0) {
        int run = 0;
        for (int b = 0; b < nb; ++b) { const int v = blockSums[b]; blockSums[b] = run; run += v; }
    }
}

__global__ __launch_bounds__(256) void scan3_k(
    const int* __restrict__ part, const int* __restrict__ blockSums,
    int* __restrict__ rowStart, int n, int nEdges)
{
    const int i = blockIdx.x * blockDim.x + threadIdx.x;
    if (i < n) rowStart[i] = part[i] + blockSums[i >> 10];
    if (i == n) rowStart[n] = nEdges;
}

__global__ __launch_bounds__(256) void fill_k(
    const int* __restrict__ src, const int* __restrict__ dst,
    int* __restrict__ cursor, int* __restrict__ eSrc, int nEdges)
{
    const int i = blockIdx.x * blockDim.x + threadIdx.x;
    if (i < nEdges) {
        const int pos = atomicAdd(&cursor[dst[i]], 1);
        eSrc[pos] = src[i];
    }
}

// ===========================================================================
// Gather aggregation (bf16): agg[i,:] = sum_{e in CSR row i} feat[eSrc[e],:]
// One wave per node; lane covers 2 columns (one uint = 2 bf16).
// ===========================================================================
__global__ __launch_bounds__(256) void gather_agg_k(
    const unsigned short* __restrict__ feat,
    const int*            __restrict__ rowStart,
    const int*            __restrict__ eSrc,
    unsigned short*       __restrict__ agg,
    int nNodes)
{
    const int node = (int)((blockIdx.x * blockDim.x + threadIdx.x) >> 6);
    if (node >= nNodes) return;
    const int lane = threadIdx.x & 63;
    const int beg = rowStart[node];
    const int end = rowStart[node + 1];

    float ax = 0.f, ay = 0.f;
    int e = beg;
    for (; e + 2 <= end; e += 2) {
        const int s0 = eSrc[e];
        const int s1 = eSrc[e + 1];
        const unsigned int v0 = *reinterpret_cast<const unsigned int*>(feat + (size_t)s0 * HID + lane * 2);
        const unsigned int v1 = *reinterpret_cast<const unsigned int*>(feat + (size_t)s1 * HID + lane * 2);
        ax += bf_lo(v0) + bf_lo(v1);
        ay += bf_hi(v0) + bf_hi(v1);
    }
    if (e < end) {
        const unsigned int v = *reinterpret_cast<const unsigned int*>(feat + (size_t)eSrc[e] * HID + lane * 2);
        ax += bf_lo(v);
        ay += bf_hi(v);
    }
    const unsigned int packed = (unsigned int)f2bf(ax) | ((unsigned int)f2bf(ay) << 16);
    *reinterpret_cast<unsigned int*>(agg + (size_t)node * HID + lane * 2) = packed;
}

// ===========================================================================
// bf16 MFMA dual-GEMM: OUT[r,:] = act( X[r,:]@Wroot^T + AGG[r,:]@Wrel^T + b )
// 128x128 tile, 4 waves (2x2, each 64x64), K=256 in 4 chunks of 64.
// LDS tiles [128][64] bf16, XOR-swizzled (pre-swizzled global src, rule #21).
// MODE 0: bf16 out + ReLU; MODE 1: f32 out, no ReLU.
// ===========================================================================
template <int MODE>
__global__ __launch_bounds__(256) void gemm_mfma_k(
    const unsigned short* __restrict__ X,
    const unsigned short* __restrict__ AGG,
    const unsigned short* __restrict__ Wroot,
    const unsigned short* __restrict__ Wrel,
    const float*          __restrict__ bias,
    void*                 __restrict__ OUTv,
    int nRows)
{
    __shared__ unsigned short Xs[128 * 64];
    __shared__ unsigned short Ws[128 * 64];

    const int tid  = threadIdx.x;
    const int lane = tid & 63;
    const int w    = tid >> 6;
    const int row0 = blockIdx.x * 128;

    const int wr = w >> 1, wc = w & 1;
    const int R0 = wr * 64, C0 = wc * 64;
    const int lr = lane & 15, lk = lane >> 4;
    const int swz = (lr & 7) << 4;           // read-side XOR (bytes)

    // staging lane decomposition: 8 rows per 1KB issue
    const int rsub    = lane >> 3;                              // 0..7
    const int srcColB = (((lane & 7) ^ rsub) << 4);             // pre-swizzled src col (bytes)
    const int stHalf  = w & 1;                                  // which 64 rows this wave stages
    const int rowMax  = nRows - 1;

    f32x4 acc[4][4];
#pragma unroll
    for (int m = 0; m < 4; ++m)
#pragma unroll
        for (int n = 0; n < 4; ++n) acc[m][n] = f32x4{0.f, 0.f, 0.f, 0.f};

#pragma unroll
    for (int half = 0; half < 2; ++half) {
        const unsigned short* F  = half ? AGG  : X;
        const unsigned short* Wm = half ? Wrel : Wroot;
#pragma unroll
        for (int c = 0; c < 2; ++c) {
            const int k0 = c * 64;  // elements
            if (w < 2) {
                // waves 0,1: stage X-tile rows [stHalf*64, +64)
#pragma unroll
                for (int q = 0; q < 8; ++q) {
                    const int row = stHalf * 64 + q * 8 + rsub;
                    const int gr  = min(row0 + row, rowMax);
                    const char* g = (const char*)(F + (size_t)gr * HID + k0) + srcColB;
                    unsigned short* l = Xs + (stHalf * 64 + q * 8) * 64;
                    gload16(g, l);
                }
            } else {
                // waves 2,3: stage W-tile (rows = output channels)
#pragma unroll
                for (int q = 0; q < 8; ++q) {
                    const int row = stHalf * 64 + q * 8 + rsub;
                    const char* g = (const char*)(Wm + (size_t)row * HID + k0) + srcColB;
                    unsigned short* l = Ws + (stHalf * 64 + q * 8) * 64;
                    gload16(g, l);
                }
            }
            __syncthreads();

#pragma unroll
            for (int ks = 0; ks < 2; ++ks) {
                bf16x8 af[4], bfr[4];
                const int kB = (ks * 64 + lk * 16) ^ swz;
#pragma unroll
                for (int m = 0; m < 4; ++m) {
                    const int row = R0 + m * 16 + lr;
                    af[m] = *reinterpret_cast<const bf16x8*>((const char*)Xs + row * 128 + kB);
                }
#pragma unroll
                for (int n = 0; n < 4; ++n) {
                    const int col = C0 + n * 16 + lr;
                    bfr[n] = *reinterpret_cast<const bf16x8*>((const char*)Ws + col * 128 + kB);
                }
#pragma unroll
                for (int m = 0; m < 4; ++m)
#pragma unroll
                    for (int n = 0; n < 4; ++n)
                        acc[m][n] = __builtin_amdgcn_mfma_f32_16x16x32_bf16(
                            af[m], bfr[n], acc[m][n], 0, 0, 0);
            }
            __syncthreads();
        }
    }

    // epilogue: C/D layout col=lane&15, row=(lane>>4)*4+j  [m89-verified]
    float bv[4];
#pragma unroll
    for (int n = 0; n < 4; ++n) bv[n] = bias[C0 + n * 16 + lr];

#pragma unroll
    for (int m = 0; m < 4; ++m) {
        const int rbase = row0 + R0 + m * 16 + lk * 4;
#pragma unroll
        for (int j = 0; j < 4; ++j) {
            const int r = rbase + j;
            if (r < nRows) {
#pragma unroll
                for (int n = 0; n < 4; ++n) {
                    const int col = C0 + n * 16 + lr;
                    float v = acc[m][n][j] + bv[n];
                    if (MODE == 0) {
                        v = fmaxf(v, 0.f);
                        ((unsigned short*)OUTv)[(size_t)r * HID + col] = f2bf(v);
                    } else {
                        ((float*)OUTv)[(size_t)r * HID + col] = v;
                    }
                }
            }
        }
    }
}

// ===========================================================================
extern "C" void kernel_launch(void* const* d_in, const int* in_sizes, int n_in,
                              void* d_out, int out_size, void* d_ws, size_t ws_size,
                              hipStream_t stream)
{
    const float* x      = (const float*)d_in[0];
    const int*   ei     = (const int*)  d_in[1];
    const float* Wrel0  = (const float*)d_in[2];
    const float* b0     = (const float*)d_in[3];
    const float* Wroot0 = (const float*)d_in[4];
    const float* Wrel1  = (const float*)d_in[5];
    const float* b1     = (const float*)d_in[6];
    const float* Wroot1 = (const float*)d_in[7];
    const float* Wrel2  = (const float*)d_in[8];
    const float* b2     = (const float*)d_in[9];
    const float* Wroot2 = (const float*)d_in[10];

    const int nNodes = in_sizes[0] / HID;   // 100000
    const int nEdges = in_sizes[1] / 2;     // 640000
    const int* srcI = ei;
    const int* dstI = ei + nEdges;
    const size_t nF = (size_t)nNodes * HID;

    float* OUT = (float*)d_out;

    // ---- workspace layout (bf16 feature buffers first, 8B-aligned)
    unsigned short* xb   = (unsigned short*)d_ws;
    unsigned short* hA   = xb + nF;
    unsigned short* hB   = hA + nF;
    unsigned short* aggb = hB + nF;
    unsigned short* wb   = aggb + nF;         // 6 x 128*128 bf16
    int* deg       = (int*)(wb + 6 * HID * HID);
    int* part      = deg + nNodes;
    int* rowStart  = part + nNodes;            // nNodes+1
    int* cursor    = rowStart + nNodes + 1;
    int* blockSums = cursor + nNodes;          // <=128
    int* eSrc      = blockSums + 128;          // nEdges

    unsigned short* Wrel0b  = wb + 0 * HID * HID;
    unsigned short* Wroot0b = wb + 1 * HID * HID;
    unsigned short* Wrel1b  = wb + 2 * HID * HID;
    unsigned short* Wroot1b = wb + 3 * HID * HID;
    unsigned short* Wrel2b  = wb + 4 * HID * HID;
    unsigned short* Wroot2b = wb + 5 * HID * HID;

    // ---- conversions
    cvt_x_k<<<(int)((nF / 4 + 255) / 256), 256, 0, stream>>>(x, xb, (int)(nF / 4));
    WPtrs wp;
    wp.s[0] = Wrel0;  wp.d[0] = Wrel0b;
    wp.s[1] = Wroot0; wp.d[1] = Wroot0b;
    wp.s[2] = Wrel1;  wp.d[2] = Wrel1b;
    wp.s[3] = Wroot1; wp.d[3] = Wroot1b;
    wp.s[4] = Wrel2;  wp.d[4] = Wrel2b;
    wp.s[5] = Wroot2; wp.d[5] = Wroot2b;
    cvt_w_k<<<dim3(16, 6), 256, 0, stream>>>(wp);

    // ---- build CSR by destination (once)
    const int nb = (nNodes + 1023) / 1024;
    hipMemsetAsync(deg, 0, (size_t)nNodes * sizeof(int), stream);
    hist_k<<<(nEdges + 255) / 256, 256, 0, stream>>>(dstI, deg, nEdges);
    scan1_k<<<nb, 256, 0, stream>>>(deg, part, blockSums, nNodes);
    scan2_k<<<1, 64, 0, stream>>>(blockSums, nb);
    scan3_k<<<(nNodes + 256) / 256, 256, 0, stream>>>(part, blockSums, rowStart, nNodes, nEdges);
    hipMemcpyAsync(cursor, rowStart, (size_t)nNodes * sizeof(int),
                   hipMemcpyDeviceToDevice, stream);
    fill_k<<<(nEdges + 255) / 256, 256, 0, stream>>>(srcI, dstI, cursor, eSrc, nEdges);

    const int aGrid = (int)(((size_t)nNodes * 64 + 255) / 256);
    const int gGrid = (nNodes + 127) / 128;

    // ---- layer 0
    gather_agg_k<<<aGrid, 256, 0, stream>>>(xb, rowStart, eSrc, aggb, nNodes);
    gemm_mfma_k<0><<<gGrid, 256, 0, stream>>>(xb, aggb, Wroot0b, Wrel0b, b0, hA, nNodes);

    // ---- layer 1
    gather_agg_k<<<aGrid, 256, 0, stream>>>(hA, rowStart, eSrc, aggb, nNodes);
    gemm_mfma_k<0><<<gGrid, 256, 0, stream>>>(hA, aggb, Wroot1b, Wrel1b, b1, hB, nNodes);

    // ---- layer 2 (f32 out, no ReLU)
    gather_agg_k<<<aGrid, 256, 0, stream>>>(hB, rowStart, eSrc, aggb, nNodes);
    gemm_mfma_k<1><<<gGrid, 256, 0, stream>>>(hB, aggb, Wroot2b, Wrel2b, b2, OUT, nNodes);
}

// Round 4
// 247.512 us; speedup vs baseline: 7.7552x; 1.2263x over previous
//
#include <hip/hip_runtime.h>

constexpr int HID = 128;

typedef __attribute__((ext_vector_type(8))) short bf16x8;
typedef __attribute__((ext_vector_type(4))) float f32x4;

__device__ __forceinline__ unsigned short f2bf(float f) {
    unsigned int u = __float_as_uint(f);
    u += 0x7fffu + ((u >> 16) & 1u);            // RNE
    return (unsigned short)(u >> 16);
}
__device__ __forceinline__ float bf_lo(unsigned int v) { return __uint_as_float(v << 16); }
__device__ __forceinline__ float bf_hi(unsigned int v) { return __uint_as_float(v & 0xffff0000u); }

__device__ __forceinline__ void gload16(const void* g, void* l) {
    __builtin_amdgcn_global_load_lds(
        (const __attribute__((address_space(1))) void*)g,
        (__attribute__((address_space(3))) void*)l, 16, 0, 0);
}

// ===========================================================================
// f32 -> bf16 conversions
// ===========================================================================
__global__ __launch_bounds__(256) void cvt_x_k(
    const float* __restrict__ in, unsigned short* __restrict__ out, int n4)
{
    const int i = blockIdx.x * 256 + threadIdx.x;
    if (i >= n4) return;
    const float4 v = reinterpret_cast<const float4*>(in)[i];
    ushort4 o;
    o.x = f2bf(v.x); o.y = f2bf(v.y); o.z = f2bf(v.z); o.w = f2bf(v.w);
    reinterpret_cast<ushort4*>(out)[i] = o;
}

struct WPtrs { const float* s[6]; unsigned short* d[6]; };
__global__ __launch_bounds__(256) void cvt_w_k(WPtrs p)
{
    const int which = blockIdx.y;
    const int i = blockIdx.x * 256 + threadIdx.x;
    if (i >= (HID * HID) / 4) return;
    const float4 v = reinterpret_cast<const float4*>(p.s[which])[i];
    ushort4 o;
    o.x = f2bf(v.x); o.y = f2bf(v.y); o.z = f2bf(v.z); o.w = f2bf(v.w);
    reinterpret_cast<ushort4*>(p.d[which])[i] = o;
}

// ===========================================================================
// CSR-by-dst construction (once per launch)
// ===========================================================================
__global__ __launch_bounds__(256) void hist_k(
    const int* __restrict__ dst, int* __restrict__ deg, int nEdges)
{
    const int i = blockIdx.x * blockDim.x + threadIdx.x;
    if (i < nEdges) atomicAdd(&deg[dst[i]], 1);
}

__global__ __launch_bounds__(256) void scan1_k(
    const int* __restrict__ deg, int* __restrict__ part,
    int* __restrict__ blockSums, int n)
{
    __shared__ int s[256];
    const int t = threadIdx.x;
    const int i = blockIdx.x * 1024 + t * 4;
    const int e0 = (i + 0 < n) ? deg[i + 0] : 0;
    const int e1 = (i + 1 < n) ? deg[i + 1] : 0;
    const int e2 = (i + 2 < n) ? deg[i + 2] : 0;
    const int e3 = (i + 3 < n) ? deg[i + 3] : 0;
    const int local = e0 + e1 + e2 + e3;
    s[t] = local;
    __syncthreads();
    for (int off = 1; off < 256; off <<= 1) {
        int v = 0;
        if (t >= off) v = s[t - off];
        __syncthreads();
        if (t >= off) s[t] += v;
        __syncthreads();
    }
    const int incl = s[t];
    int excl = incl - local;
    if (t == 255) blockSums[blockIdx.x] = incl;
    if (i + 0 < n) part[i + 0] = excl; excl += e0;
    if (i + 1 < n) part[i + 1] = excl; excl += e1;
    if (i + 2 < n) part[i + 2] = excl; excl += e2;
    if (i + 3 < n) part[i + 3] = excl;
}

// Parallel exclusive scan over <=128 block sums (one 128-thread block).
__global__ __launch_bounds__(128) void scan2_k(int* __restrict__ blockSums, int nb)
{
    __shared__ int s[128];
    const int t = threadIdx.x;
    const int v = (t < nb) ? blockSums[t] : 0;
    s[t] = v;
    __syncthreads();
    for (int off = 1; off < 128; off <<= 1) {
        int u = 0;
        if (t >= off) u = s[t - off];
        __syncthreads();
        if (t >= off) s[t] += u;
        __syncthreads();
    }
    if (t < nb) blockSums[t] = s[t] - v;   // exclusive
}

__global__ __launch_bounds__(256) void scan3_k(
    const int* __restrict__ part, const int* __restrict__ blockSums,
    int* __restrict__ rowStart, int n, int nEdges)
{
    const int i = blockIdx.x * blockDim.x + threadIdx.x;
    if (i < n) rowStart[i] = part[i] + blockSums[i >> 10];
    if (i == n) rowStart[n] = nEdges;
}

__global__ __launch_bounds__(256) void fill_k(
    const int* __restrict__ src, const int* __restrict__ dst,
    int* __restrict__ cursor, int* __restrict__ eSrc, int nEdges)
{
    const int i = blockIdx.x * blockDim.x + threadIdx.x;
    if (i < nEdges) {
        const int pos = atomicAdd(&cursor[dst[i]], 1);
        eSrc[pos] = src[i];
    }
}

// ===========================================================================
// Gather aggregation (bf16): agg[i,:] = sum_{e in CSR row i} feat[eSrc[e],:]
// One wave per node. Edge indices for a 64-edge chunk are loaded with ONE
// lane-parallel load and broadcast via __shfl; feature-row loads issued in
// batches of 8 (then 4/2/1) so up to 8 loads are in flight per wave.
// ===========================================================================
__global__ __launch_bounds__(256) void gather_agg_k(
    const unsigned short* __restrict__ feat,
    const int*            __restrict__ rowStart,
    const int*            __restrict__ eSrc,
    unsigned short*       __restrict__ agg,
    int nNodes)
{
    const int node = (int)((blockIdx.x * blockDim.x + threadIdx.x) >> 6);
    if (node >= nNodes) return;
    const int lane = threadIdx.x & 63;
    const int beg = rowStart[node];
    const int end = rowStart[node + 1];
    const size_t colOff = (size_t)lane * 2;

    float ax = 0.f, ay = 0.f;

    for (int base = beg; base < end; base += 64) {
        const int cnt = min(64, end - base);
        const int si = eSrc[base + min(lane, cnt - 1)];   // one load: 64 indices

        int j = 0;
        for (; j + 8 <= cnt; j += 8) {
            unsigned int v[8];
#pragma unroll
            for (int q = 0; q < 8; ++q) {
                const int s = __shfl(si, j + q, 64);
                v[q] = *reinterpret_cast<const unsigned int*>(feat + (size_t)s * HID + colOff);
            }
#pragma unroll
            for (int q = 0; q < 8; ++q) { ax += bf_lo(v[q]); ay += bf_hi(v[q]); }
        }
        if (j + 4 <= cnt) {
            unsigned int v[4];
#pragma unroll
            for (int q = 0; q < 4; ++q) {
                const int s = __shfl(si, j + q, 64);
                v[q] = *reinterpret_cast<const unsigned int*>(feat + (size_t)s * HID + colOff);
            }
#pragma unroll
            for (int q = 0; q < 4; ++q) { ax += bf_lo(v[q]); ay += bf_hi(v[q]); }
            j += 4;
        }
        if (j + 2 <= cnt) {
            const int s0 = __shfl(si, j, 64);
            const int s1 = __shfl(si, j + 1, 64);
            const unsigned int v0 = *reinterpret_cast<const unsigned int*>(feat + (size_t)s0 * HID + colOff);
            const unsigned int v1 = *reinterpret_cast<const unsigned int*>(feat + (size_t)s1 * HID + colOff);
            ax += bf_lo(v0) + bf_lo(v1);
            ay += bf_hi(v0) + bf_hi(v1);
            j += 2;
        }
        if (j < cnt) {
            const int s = __shfl(si, j, 64);
            const unsigned int v = *reinterpret_cast<const unsigned int*>(feat + (size_t)s * HID + colOff);
            ax += bf_lo(v);
            ay += bf_hi(v);
        }
    }

    const unsigned int packed = (unsigned int)f2bf(ax) | ((unsigned int)f2bf(ay) << 16);
    *reinterpret_cast<unsigned int*>(agg + (size_t)node * HID + colOff) = packed;
}

// ===========================================================================
// bf16 MFMA dual-GEMM: OUT[r,:] = act( X[r,:]@Wroot^T + AGG[r,:]@Wrel^T + b )
// 128x128 tile, 4 waves (2x2, each 64x64), K=256 in 4 chunks of 64.
// LDS tiles [128][64] bf16, XOR-swizzled (pre-swizzled global src, rule #21).
// MODE 0: bf16 out + ReLU; MODE 1: f32 out, no ReLU.
// ===========================================================================
template <int MODE>
__global__ __launch_bounds__(256) void gemm_mfma_k(
    const unsigned short* __restrict__ X,
    const unsigned short* __restrict__ AGG,
    const unsigned short* __restrict__ Wroot,
    const unsigned short* __restrict__ Wrel,
    const float*          __restrict__ bias,
    void*                 __restrict__ OUTv,
    int nRows)
{
    __shared__ unsigned short Xs[128 * 64];
    __shared__ unsigned short Ws[128 * 64];

    const int tid  = threadIdx.x;
    const int lane = tid & 63;
    const int w    = tid >> 6;
    const int row0 = blockIdx.x * 128;

    const int wr = w >> 1, wc = w & 1;
    const int R0 = wr * 64, C0 = wc * 64;
    const int lr = lane & 15, lk = lane >> 4;
    const int swz = (lr & 7) << 4;           // read-side XOR (bytes)

    const int rsub    = lane >> 3;                              // 0..7
    const int srcColB = (((lane & 7) ^ rsub) << 4);             // pre-swizzled src col (bytes)
    const int stHalf  = w & 1;
    const int rowMax  = nRows - 1;

    f32x4 acc[4][4];
#pragma unroll
    for (int m = 0; m < 4; ++m)
#pragma unroll
        for (int n = 0; n < 4; ++n) acc[m][n] = f32x4{0.f, 0.f, 0.f, 0.f};

#pragma unroll
    for (int half = 0; half < 2; ++half) {
        const unsigned short* F  = half ? AGG  : X;
        const unsigned short* Wm = half ? Wrel : Wroot;
#pragma unroll
        for (int c = 0; c < 2; ++c) {
            const int k0 = c * 64;
            if (w < 2) {
#pragma unroll
                for (int q = 0; q < 8; ++q) {
                    const int row = stHalf * 64 + q * 8 + rsub;
                    const int gr  = min(row0 + row, rowMax);
                    const char* g = (const char*)(F + (size_t)gr * HID + k0) + srcColB;
                    unsigned short* l = Xs + (stHalf * 64 + q * 8) * 64;
                    gload16(g, l);
                }
            } else {
#pragma unroll
                for (int q = 0; q < 8; ++q) {
                    const int row = stHalf * 64 + q * 8 + rsub;
                    const char* g = (const char*)(Wm + (size_t)row * HID + k0) + srcColB;
                    unsigned short* l = Ws + (stHalf * 64 + q * 8) * 64;
                    gload16(g, l);
                }
            }
            __syncthreads();

#pragma unroll
            for (int ks = 0; ks < 2; ++ks) {
                bf16x8 af[4], bfr[4];
                const int kB = (ks * 64 + lk * 16) ^ swz;
#pragma unroll
                for (int m = 0; m < 4; ++m) {
                    const int row = R0 + m * 16 + lr;
                    af[m] = *reinterpret_cast<const bf16x8*>((const char*)Xs + row * 128 + kB);
                }
#pragma unroll
                for (int n = 0; n < 4; ++n) {
                    const int col = C0 + n * 16 + lr;
                    bfr[n] = *reinterpret_cast<const bf16x8*>((const char*)Ws + col * 128 + kB);
                }
#pragma unroll
                for (int m = 0; m < 4; ++m)
#pragma unroll
                    for (int n = 0; n < 4; ++n)
                        acc[m][n] = __builtin_amdgcn_mfma_f32_16x16x32_bf16(
                            af[m], bfr[n], acc[m][n], 0, 0, 0);
            }
            __syncthreads();
        }
    }

    float bv[4];
#pragma unroll
    for (int n = 0; n < 4; ++n) bv[n] = bias[C0 + n * 16 + lr];

#pragma unroll
    for (int m = 0; m < 4; ++m) {
        const int rbase = row0 + R0 + m * 16 + lk * 4;
#pragma unroll
        for (int j = 0; j < 4; ++j) {
            const int r = rbase + j;
            if (r < nRows) {
#pragma unroll
                for (int n = 0; n < 4; ++n) {
                    const int col = C0 + n * 16 + lr;
                    float v = acc[m][n][j] + bv[n];
                    if (MODE == 0) {
                        v = fmaxf(v, 0.f);
                        ((unsigned short*)OUTv)[(size_t)r * HID + col] = f2bf(v);
                    } else {
                        ((float*)OUTv)[(size_t)r * HID + col] = v;
                    }
                }
            }
        }
    }
}

// ===========================================================================
extern "C" void kernel_launch(void* const* d_in, const int* in_sizes, int n_in,
                              void* d_out, int out_size, void* d_ws, size_t ws_size,
                              hipStream_t stream)
{
    const float* x      = (const float*)d_in[0];
    const int*   ei     = (const int*)  d_in[1];
    const float* Wrel0  = (const float*)d_in[2];
    const float* b0     = (const float*)d_in[3];
    const float* Wroot0 = (const float*)d_in[4];
    const float* Wrel1  = (const float*)d_in[5];
    const float* b1     = (const float*)d_in[6];
    const float* Wroot1 = (const float*)d_in[7];
    const float* Wrel2  = (const float*)d_in[8];
    const float* b2     = (const float*)d_in[9];
    const float* Wroot2 = (const float*)d_in[10];

    const int nNodes = in_sizes[0] / HID;   // 100000
    const int nEdges = in_sizes[1] / 2;     // 640000
    const int* srcI = ei;
    const int* dstI = ei + nEdges;
    const size_t nF = (size_t)nNodes * HID;

    float* OUT = (float*)d_out;

    // ---- workspace layout
    unsigned short* xb   = (unsigned short*)d_ws;
    unsigned short* hA   = xb + nF;
    unsigned short* hB   = hA + nF;
    unsigned short* aggb = hB + nF;
    unsigned short* wb   = aggb + nF;          // 6 x 128*128 bf16
    int* deg       = (int*)(wb + 6 * HID * HID);
    int* part      = deg + nNodes;
    int* rowStart  = part + nNodes;            // nNodes+1
    int* cursor    = rowStart + nNodes + 1;
    int* blockSums = cursor + nNodes;          // <=128
    int* eSrc      = blockSums + 128;          // nEdges

    unsigned short* Wrel0b  = wb + 0 * HID * HID;
    unsigned short* Wroot0b = wb + 1 * HID * HID;
    unsigned short* Wrel1b  = wb + 2 * HID * HID;
    unsigned short* Wroot1b = wb + 3 * HID * HID;
    unsigned short* Wrel2b  = wb + 4 * HID * HID;
    unsigned short* Wroot2b = wb + 5 * HID * HID;

    // ---- conversions
    cvt_x_k<<<(int)((nF / 4 + 255) / 256), 256, 0, stream>>>(x, xb, (int)(nF / 4));
    WPtrs wp;
    wp.s[0] = Wrel0;  wp.d[0] = Wrel0b;
    wp.s[1] = Wroot0; wp.d[1] = Wroot0b;
    wp.s[2] = Wrel1;  wp.d[2] = Wrel1b;
    wp.s[3] = Wroot1; wp.d[3] = Wroot1b;
    wp.s[4] = Wrel2;  wp.d[4] = Wrel2b;
    wp.s[5] = Wroot2; wp.d[5] = Wroot2b;
    cvt_w_k<<<dim3(16, 6), 256, 0, stream>>>(wp);

    // ---- build CSR by destination (once)
    const int nb = (nNodes + 1023) / 1024;
    hipMemsetAsync(deg, 0, (size_t)nNodes * sizeof(int), stream);
    hist_k<<<(nEdges + 255) / 256, 256, 0, stream>>>(dstI, deg, nEdges);
    scan1_k<<<nb, 256, 0, stream>>>(deg, part, blockSums, nNodes);
    scan2_k<<<1, 128, 0, stream>>>(blockSums, nb);
    scan3_k<<<(nNodes + 256) / 256, 256, 0, stream>>>(part, blockSums, rowStart, nNodes, nEdges);
    hipMemcpyAsync(cursor, rowStart, (size_t)nNodes * sizeof(int),
                   hipMemcpyDeviceToDevice, stream);
    fill_k<<<(nEdges + 255) / 256, 256, 0, stream>>>(srcI, dstI, cursor, eSrc, nEdges);

    const int aGrid = (int)(((size_t)nNodes * 64 + 255) / 256);
    const int gGrid = (nNodes + 127) / 128;

    // ---- layer 0
    gather_agg_k<<<aGrid, 256, 0, stream>>>(xb, rowStart, eSrc, aggb, nNodes);
    gemm_mfma_k<0><<<gGrid, 256, 0, stream>>>(xb, aggb, Wroot0b, Wrel0b, b0, hA, nNodes);

    // ---- layer 1
    gather_agg_k<<<aGrid, 256, 0, stream>>>(hA, rowStart, eSrc, aggb, nNodes);
    gemm_mfma_k<0><<<gGrid, 256, 0, stream>>>(hA, aggb, Wroot1b, Wrel1b, b1, hB, nNodes);

    // ---- layer 2 (f32 out, no ReLU)
    gather_agg_k<<<aGrid, 256, 0, stream>>>(hB, rowStart, eSrc, aggb, nNodes);
    gemm_mfma_k<1><<<gGrid, 256, 0, stream>>>(hB, aggb, Wroot2b, Wrel2b, b2, OUT, nNodes);
}

// Round 5
// 244.571 us; speedup vs baseline: 7.8485x; 1.0120x over previous
//
#include <hip/hip_runtime.h>

constexpr int HID = 128;

typedef __attribute__((ext_vector_type(8))) short bf16x8;
typedef __attribute__((ext_vector_type(4))) float f32x4;

__device__ __forceinline__ unsigned short f2bf(float f) {
    unsigned int u = __float_as_uint(f);
    u += 0x7fffu + ((u >> 16) & 1u);            // RNE
    return (unsigned short)(u >> 16);
}
__device__ __forceinline__ float bf_lo(unsigned int v) { return __uint_as_float(v << 16); }
__device__ __forceinline__ float bf_hi(unsigned int v) { return __uint_as_float(v & 0xffff0000u); }

__device__ __forceinline__ void gload16(const void* g, void* l) {
    __builtin_amdgcn_global_load_lds(
        (const __attribute__((address_space(1))) void*)g,
        (__attribute__((address_space(3))) void*)l, 16, 0, 0);
}

// ===========================================================================
// f32 -> bf16 conversions
// ===========================================================================
__global__ __launch_bounds__(256) void cvt_x_k(
    const float* __restrict__ in, unsigned short* __restrict__ out, int n4)
{
    const int i = blockIdx.x * 256 + threadIdx.x;
    if (i >= n4) return;
    const float4 v = reinterpret_cast<const float4*>(in)[i];
    ushort4 o;
    o.x = f2bf(v.x); o.y = f2bf(v.y); o.z = f2bf(v.z); o.w = f2bf(v.w);
    reinterpret_cast<ushort4*>(out)[i] = o;
}

struct WPtrs { const float* s[6]; unsigned short* d[6]; };
__global__ __launch_bounds__(256) void cvt_w_k(WPtrs p)
{
    const int which = blockIdx.y;
    const int i = blockIdx.x * 256 + threadIdx.x;
    if (i >= (HID * HID) / 4) return;
    const float4 v = reinterpret_cast<const float4*>(p.s[which])[i];
    ushort4 o;
    o.x = f2bf(v.x); o.y = f2bf(v.y); o.z = f2bf(v.z); o.w = f2bf(v.w);
    reinterpret_cast<ushort4*>(p.d[which])[i] = o;
}

// ===========================================================================
// CSR-by-dst construction (once per launch)
// ===========================================================================
__global__ __launch_bounds__(256) void hist_k(
    const int* __restrict__ dst, int* __restrict__ deg, int nEdges)
{
    const int i = blockIdx.x * blockDim.x + threadIdx.x;
    if (i < nEdges) atomicAdd(&deg[dst[i]], 1);
}

__global__ __launch_bounds__(256) void scan1_k(
    const int* __restrict__ deg, int* __restrict__ part,
    int* __restrict__ blockSums, int n)
{
    __shared__ int s[256];
    const int t = threadIdx.x;
    const int i = blockIdx.x * 1024 + t * 4;
    const int e0 = (i + 0 < n) ? deg[i + 0] : 0;
    const int e1 = (i + 1 < n) ? deg[i + 1] : 0;
    const int e2 = (i + 2 < n) ? deg[i + 2] : 0;
    const int e3 = (i + 3 < n) ? deg[i + 3] : 0;
    const int local = e0 + e1 + e2 + e3;
    s[t] = local;
    __syncthreads();
    for (int off = 1; off < 256; off <<= 1) {
        int v = 0;
        if (t >= off) v = s[t - off];
        __syncthreads();
        if (t >= off) s[t] += v;
        __syncthreads();
    }
    const int incl = s[t];
    int excl = incl - local;
    if (t == 255) blockSums[blockIdx.x] = incl;
    if (i + 0 < n) part[i + 0] = excl; excl += e0;
    if (i + 1 < n) part[i + 1] = excl; excl += e1;
    if (i + 2 < n) part[i + 2] = excl; excl += e2;
    if (i + 3 < n) part[i + 3] = excl;
}

// Parallel exclusive scan over <=128 block sums.
__global__ __launch_bounds__(128) void scan2_k(int* __restrict__ blockSums, int nb)
{
    __shared__ int s[128];
    const int t = threadIdx.x;
    const int v = (t < nb) ? blockSums[t] : 0;
    s[t] = v;
    __syncthreads();
    for (int off = 1; off < 128; off <<= 1) {
        int u = 0;
        if (t >= off) u = s[t - off];
        __syncthreads();
        if (t >= off) s[t] += u;
        __syncthreads();
    }
    if (t < nb) blockSums[t] = s[t] - v;   // exclusive
}

// rowStart AND cursor written here (memcpy dispatch eliminated).
__global__ __launch_bounds__(256) void scan3_k(
    const int* __restrict__ part, const int* __restrict__ blockSums,
    int* __restrict__ rowStart, int* __restrict__ cursor, int n, int nEdges)
{
    const int i = blockIdx.x * blockDim.x + threadIdx.x;
    if (i < n) {
        const int v = part[i] + blockSums[i >> 10];
        rowStart[i] = v;
        cursor[i]   = v;
    }
    if (i == n) rowStart[n] = nEdges;
}

__global__ __launch_bounds__(256) void fill_k(
    const int* __restrict__ src, const int* __restrict__ dst,
    int* __restrict__ cursor, int* __restrict__ eSrc, int nEdges)
{
    const int i = blockIdx.x * blockDim.x + threadIdx.x;
    if (i < nEdges) {
        const int pos = atomicAdd(&cursor[dst[i]], 1);
        eSrc[pos] = src[i];
    }
}

// ===========================================================================
// Gather aggregation (bf16): one wave per node, batched ILP (8/4/2/1).
// ===========================================================================
__global__ __launch_bounds__(256) void gather_agg_k(
    const unsigned short* __restrict__ feat,
    const int*            __restrict__ rowStart,
    const int*            __restrict__ eSrc,
    unsigned short*       __restrict__ agg,
    int nNodes)
{
    const int node = (int)((blockIdx.x * blockDim.x + threadIdx.x) >> 6);
    if (node >= nNodes) return;
    const int lane = threadIdx.x & 63;
    const int beg = rowStart[node];
    const int end = rowStart[node + 1];
    const size_t colOff = (size_t)lane * 2;

    float ax = 0.f, ay = 0.f;

    for (int base = beg; base < end; base += 64) {
        const int cnt = min(64, end - base);
        const int si = eSrc[base + min(lane, cnt - 1)];   // one load: 64 indices

        int j = 0;
        for (; j + 8 <= cnt; j += 8) {
            unsigned int v[8];
#pragma unroll
            for (int q = 0; q < 8; ++q) {
                const int s = __shfl(si, j + q, 64);
                v[q] = *reinterpret_cast<const unsigned int*>(feat + (size_t)s * HID + colOff);
            }
#pragma unroll
            for (int q = 0; q < 8; ++q) { ax += bf_lo(v[q]); ay += bf_hi(v[q]); }
        }
        if (j + 4 <= cnt) {
            unsigned int v[4];
#pragma unroll
            for (int q = 0; q < 4; ++q) {
                const int s = __shfl(si, j + q, 64);
                v[q] = *reinterpret_cast<const unsigned int*>(feat + (size_t)s * HID + colOff);
            }
#pragma unroll
            for (int q = 0; q < 4; ++q) { ax += bf_lo(v[q]); ay += bf_hi(v[q]); }
            j += 4;
        }
        if (j + 2 <= cnt) {
            const int s0 = __shfl(si, j, 64);
            const int s1 = __shfl(si, j + 1, 64);
            const unsigned int v0 = *reinterpret_cast<const unsigned int*>(feat + (size_t)s0 * HID + colOff);
            const unsigned int v1 = *reinterpret_cast<const unsigned int*>(feat + (size_t)s1 * HID + colOff);
            ax += bf_lo(v0) + bf_lo(v1);
            ay += bf_hi(v0) + bf_hi(v1);
            j += 2;
        }
        if (j < cnt) {
            const int s = __shfl(si, j, 64);
            const unsigned int v = *reinterpret_cast<const unsigned int*>(feat + (size_t)s * HID + colOff);
            ax += bf_lo(v);
            ay += bf_hi(v);
        }
    }

    const unsigned int packed = (unsigned int)f2bf(ax) | ((unsigned int)f2bf(ay) << 16);
    *reinterpret_cast<unsigned int*>(agg + (size_t)node * HID + colOff) = packed;
}

// ===========================================================================
// bf16 MFMA dual-GEMM, 2-phase double-buffered pipeline (T3-minimum):
// STAGE(t+1) issued before compute(t); raw s_barrier + counted vmcnt(8) so
// 8 global_load_lds per wave stay in flight across the barrier.
// ===========================================================================
__device__ __forceinline__ void stage_tile(
    const unsigned short* __restrict__ F, const unsigned short* __restrict__ Wm,
    unsigned short* XsBuf, unsigned short* WsBuf,
    int w, int stHalf, int rsub, int srcColB, int k0, int row0, int rowMax)
{
    if (w < 2) {
#pragma unroll
        for (int q = 0; q < 8; ++q) {
            const int row = stHalf * 64 + q * 8 + rsub;
            const int gr  = min(row0 + row, rowMax);
            gload16((const char*)(F + (size_t)gr * HID + k0) + srcColB,
                    XsBuf + (stHalf * 64 + q * 8) * 64);
        }
    } else {
#pragma unroll
        for (int q = 0; q < 8; ++q) {
            const int row = stHalf * 64 + q * 8 + rsub;
            gload16((const char*)(Wm + (size_t)row * HID + k0) + srcColB,
                    WsBuf + (stHalf * 64 + q * 8) * 64);
        }
    }
}

template <int MODE>
__global__ __launch_bounds__(256) void gemm_mfma_k(
    const unsigned short* __restrict__ X,
    const unsigned short* __restrict__ AGG,
    const unsigned short* __restrict__ Wroot,
    const unsigned short* __restrict__ Wrel,
    const float*          __restrict__ bias,
    void*                 __restrict__ OUTv,
    int nRows)
{
    __shared__ unsigned short Xs[2][128 * 64];
    __shared__ unsigned short Ws[2][128 * 64];

    const int tid  = threadIdx.x;
    const int lane = tid & 63;
    const int w    = tid >> 6;
    const int row0 = blockIdx.x * 128;

    const int wr = w >> 1, wc = w & 1;
    const int R0 = wr * 64, C0 = wc * 64;
    const int lr = lane & 15, lk = lane >> 4;
    const int swz = (lr & 7) << 4;           // read-side XOR (bytes)

    const int rsub    = lane >> 3;
    const int srcColB = (((lane & 7) ^ rsub) << 4);   // pre-swizzled src col (bytes)
    const int stHalf  = w & 1;
    const int rowMax  = nRows - 1;

    f32x4 acc[4][4];
#pragma unroll
    for (int m = 0; m < 4; ++m)
#pragma unroll
        for (int n = 0; n < 4; ++n) acc[m][n] = f32x4{0.f, 0.f, 0.f, 0.f};

    // phase t: t<2 -> (X,Wroot), t>=2 -> (AGG,Wrel); k0 = (t&1)*64
    stage_tile(X, Wroot, Xs[0], Ws[0], w, stHalf, rsub, srcColB, 0, row0, rowMax);

#pragma unroll
    for (int t = 0; t < 4; ++t) {
        const int cur = t & 1;
        if (t < 3) {
            const unsigned short* Fn = (t + 1 < 2) ? X : AGG;
            const unsigned short* Wn = (t + 1 < 2) ? Wroot : Wrel;
            stage_tile(Fn, Wn, Xs[cur ^ 1], Ws[cur ^ 1],
                       w, stHalf, rsub, srcColB, ((t + 1) & 1) * 64, row0, rowMax);
            asm volatile("s_waitcnt vmcnt(8)" ::: "memory");   // phase-t loads landed
        } else {
            asm volatile("s_waitcnt vmcnt(0)" ::: "memory");   // drain final phase
        }
        __builtin_amdgcn_s_barrier();

#pragma unroll
        for (int ks = 0; ks < 2; ++ks) {
            bf16x8 af[4], bfr[4];
            const int kB = (ks * 64 + lk * 16) ^ swz;
#pragma unroll
            for (int m = 0; m < 4; ++m) {
                const int row = R0 + m * 16 + lr;
                af[m] = *reinterpret_cast<const bf16x8*>((const char*)Xs[cur] + row * 128 + kB);
            }
#pragma unroll
            for (int n = 0; n < 4; ++n) {
                const int col = C0 + n * 16 + lr;
                bfr[n] = *reinterpret_cast<const bf16x8*>((const char*)Ws[cur] + col * 128 + kB);
            }
#pragma unroll
            for (int m = 0; m < 4; ++m)
#pragma unroll
                for (int n = 0; n < 4; ++n)
                    acc[m][n] = __builtin_amdgcn_mfma_f32_16x16x32_bf16(
                        af[m], bfr[n], acc[m][n], 0, 0, 0);
        }
        if (t < 3) __builtin_amdgcn_s_barrier();   // buffer free for restage
    }

    float bv[4];
#pragma unroll
    for (int n = 0; n < 4; ++n) bv[n] = bias[C0 + n * 16 + lr];

#pragma unroll
    for (int m = 0; m < 4; ++m) {
        const int rbase = row0 + R0 + m * 16 + lk * 4;
#pragma unroll
        for (int j = 0; j < 4; ++j) {
            const int r = rbase + j;
            if (r < nRows) {
#pragma unroll
                for (int n = 0; n < 4; ++n) {
                    const int col = C0 + n * 16 + lr;
                    float v = acc[m][n][j] + bv[n];
                    if (MODE == 0) {
                        v = fmaxf(v, 0.f);
                        ((unsigned short*)OUTv)[(size_t)r * HID + col] = f2bf(v);
                    } else {
                        ((float*)OUTv)[(size_t)r * HID + col] = v;
                    }
                }
            }
        }
    }
}

// ===========================================================================
extern "C" void kernel_launch(void* const* d_in, const int* in_sizes, int n_in,
                              void* d_out, int out_size, void* d_ws, size_t ws_size,
                              hipStream_t stream)
{
    const float* x      = (const float*)d_in[0];
    const int*   ei     = (const int*)  d_in[1];
    const float* Wrel0  = (const float*)d_in[2];
    const float* b0     = (const float*)d_in[3];
    const float* Wroot0 = (const float*)d_in[4];
    const float* Wrel1  = (const float*)d_in[5];
    const float* b1     = (const float*)d_in[6];
    const float* Wroot1 = (const float*)d_in[7];
    const float* Wrel2  = (const float*)d_in[8];
    const float* b2     = (const float*)d_in[9];
    const float* Wroot2 = (const float*)d_in[10];

    const int nNodes = in_sizes[0] / HID;   // 100000
    const int nEdges = in_sizes[1] / 2;     // 640000
    const int* srcI = ei;
    const int* dstI = ei + nEdges;
    const size_t nF = (size_t)nNodes * HID;

    float* OUT = (float*)d_out;

    // ---- workspace layout
    unsigned short* xb   = (unsigned short*)d_ws;
    unsigned short* hA   = xb + nF;
    unsigned short* hB   = hA + nF;
    unsigned short* aggb = hB + nF;
    unsigned short* wb   = aggb + nF;          // 6 x 128*128 bf16
    int* deg       = (int*)(wb + 6 * HID * HID);
    int* part      = deg + nNodes;
    int* rowStart  = part + nNodes;            // nNodes+1
    int* cursor    = rowStart + nNodes + 1;
    int* blockSums = cursor + nNodes;          // <=128
    int* eSrc      = blockSums + 128;          // nEdges

    unsigned short* Wrel0b  = wb + 0 * HID * HID;
    unsigned short* Wroot0b = wb + 1 * HID * HID;
    unsigned short* Wrel1b  = wb + 2 * HID * HID;
    unsigned short* Wroot1b = wb + 3 * HID * HID;
    unsigned short* Wrel2b  = wb + 4 * HID * HID;
    unsigned short* Wroot2b = wb + 5 * HID * HID;

    // ---- conversions
    cvt_x_k<<<(int)((nF / 4 + 255) / 256), 256, 0, stream>>>(x, xb, (int)(nF / 4));
    WPtrs wp;
    wp.s[0] = Wrel0;  wp.d[0] = Wrel0b;
    wp.s[1] = Wroot0; wp.d[1] = Wroot0b;
    wp.s[2] = Wrel1;  wp.d[2] = Wrel1b;
    wp.s[3] = Wroot1; wp.d[3] = Wroot1b;
    wp.s[4] = Wrel2;  wp.d[4] = Wrel2b;
    wp.s[5] = Wroot2; wp.d[5] = Wroot2b;
    cvt_w_k<<<dim3(16, 6), 256, 0, stream>>>(wp);

    // ---- build CSR by destination (once)
    const int nb = (nNodes + 1023) / 1024;
    hipMemsetAsync(deg, 0, (size_t)nNodes * sizeof(int), stream);
    hist_k<<<(nEdges + 255) / 256, 256, 0, stream>>>(dstI, deg, nEdges);
    scan1_k<<<nb, 256, 0, stream>>>(deg, part, blockSums, nNodes);
    scan2_k<<<1, 128, 0, stream>>>(blockSums, nb);
    scan3_k<<<(nNodes + 256) / 256, 256, 0, stream>>>(part, blockSums, rowStart, cursor, nNodes, nEdges);
    fill_k<<<(nEdges + 255) / 256, 256, 0, stream>>>(srcI, dstI, cursor, eSrc, nEdges);

    const int aGrid = (int)(((size_t)nNodes * 64 + 255) / 256);
    const int gGrid = (nNodes + 127) / 128;

    // ---- layer 0
    gather_agg_k<<<aGrid, 256, 0, stream>>>(xb, rowStart, eSrc, aggb, nNodes);
    gemm_mfma_k<0><<<gGrid, 256, 0, stream>>>(xb, aggb, Wroot0b, Wrel0b, b0, hA, nNodes);

    // ---- layer 1
    gather_agg_k<<<aGrid, 256, 0, stream>>>(hA, rowStart, eSrc, aggb, nNodes);
    gemm_mfma_k<0><<<gGrid, 256, 0, stream>>>(hA, aggb, Wroot1b, Wrel1b, b1, hB, nNodes);

    // ---- layer 2 (f32 out, no ReLU)
    gather_agg_k<<<aGrid, 256, 0, stream>>>(hB, rowStart, eSrc, aggb, nNodes);
    gemm_mfma_k<1><<<gGrid, 256, 0, stream>>>(hB, aggb, Wroot2b, Wrel2b, b2, OUT, nNodes);
}

// Round 6
// 244.198 us; speedup vs baseline: 7.8605x; 1.0015x over previous
//
#include <hip/hip_runtime.h>

constexpr int HID = 128;

typedef __attribute__((ext_vector_type(8))) short bf16x8;
typedef __attribute__((ext_vector_type(4))) float f32x4;

__device__ __forceinline__ unsigned short f2bf(float f) {
    unsigned int u = __float_as_uint(f);
    u += 0x7fffu + ((u >> 16) & 1u);            // RNE
    return (unsigned short)(u >> 16);
}
__device__ __forceinline__ float bf_lo(unsigned int v) { return __uint_as_float(v << 16); }
__device__ __forceinline__ float bf_hi(unsigned int v) { return __uint_as_float(v & 0xffff0000u); }

__device__ __forceinline__ void gload16(const void* g, void* l) {
    __builtin_amdgcn_global_load_lds(
        (const __attribute__((address_space(1))) void*)g,
        (__attribute__((address_space(3))) void*)l, 16, 0, 0);
}

// ===========================================================================
// f32 -> bf16 conversions
// ===========================================================================
__global__ __launch_bounds__(256) void cvt_x_k(
    const float* __restrict__ in, unsigned short* __restrict__ out, int n4)
{
    const int i = blockIdx.x * 256 + threadIdx.x;
    if (i >= n4) return;
    const float4 v = reinterpret_cast<const float4*>(in)[i];
    ushort4 o;
    o.x = f2bf(v.x); o.y = f2bf(v.y); o.z = f2bf(v.z); o.w = f2bf(v.w);
    reinterpret_cast<ushort4*>(out)[i] = o;
}

struct WPtrs { const float* s[6]; unsigned short* d[6]; };
__global__ __launch_bounds__(256) void cvt_w_k(WPtrs p)
{
    const int which = blockIdx.y;
    const int i = blockIdx.x * 256 + threadIdx.x;
    if (i >= (HID * HID) / 4) return;
    const float4 v = reinterpret_cast<const float4*>(p.s[which])[i];
    ushort4 o;
    o.x = f2bf(v.x); o.y = f2bf(v.y); o.z = f2bf(v.z); o.w = f2bf(v.w);
    reinterpret_cast<ushort4*>(p.d[which])[i] = o;
}

// ===========================================================================
// CSR-by-dst construction (once per launch)
// ===========================================================================
__global__ __launch_bounds__(256) void hist_k(
    const int* __restrict__ dst, int* __restrict__ deg, int nEdges)
{
    const int i = blockIdx.x * blockDim.x + threadIdx.x;
    if (i < nEdges) atomicAdd(&deg[dst[i]], 1);
}

__global__ __launch_bounds__(256) void scan1_k(
    const int* __restrict__ deg, int* __restrict__ part,
    int* __restrict__ blockSums, int n)
{
    __shared__ int s[256];
    const int t = threadIdx.x;
    const int i = blockIdx.x * 1024 + t * 4;
    const int e0 = (i + 0 < n) ? deg[i + 0] : 0;
    const int e1 = (i + 1 < n) ? deg[i + 1] : 0;
    const int e2 = (i + 2 < n) ? deg[i + 2] : 0;
    const int e3 = (i + 3 < n) ? deg[i + 3] : 0;
    const int local = e0 + e1 + e2 + e3;
    s[t] = local;
    __syncthreads();
    for (int off = 1; off < 256; off <<= 1) {
        int v = 0;
        if (t >= off) v = s[t - off];
        __syncthreads();
        if (t >= off) s[t] += v;
        __syncthreads();
    }
    const int incl = s[t];
    int excl = incl - local;
    if (t == 255) blockSums[blockIdx.x] = incl;
    if (i + 0 < n) part[i + 0] = excl; excl += e0;
    if (i + 1 < n) part[i + 1] = excl; excl += e1;
    if (i + 2 < n) part[i + 2] = excl; excl += e2;
    if (i + 3 < n) part[i + 3] = excl;
}

// Parallel exclusive scan over <=128 block sums.
__global__ __launch_bounds__(128) void scan2_k(int* __restrict__ blockSums, int nb)
{
    __shared__ int s[128];
    const int t = threadIdx.x;
    const int v = (t < nb) ? blockSums[t] : 0;
    s[t] = v;
    __syncthreads();
    for (int off = 1; off < 128; off <<= 1) {
        int u = 0;
        if (t >= off) u = s[t - off];
        __syncthreads();
        if (t >= off) s[t] += u;
        __syncthreads();
    }
    if (t < nb) blockSums[t] = s[t] - v;   // exclusive
}

// rowStart AND cursor written here (memcpy dispatch eliminated).
__global__ __launch_bounds__(256) void scan3_k(
    const int* __restrict__ part, const int* __restrict__ blockSums,
    int* __restrict__ rowStart, int* __restrict__ cursor, int n, int nEdges)
{
    const int i = blockIdx.x * blockDim.x + threadIdx.x;
    if (i < n) {
        const int v = part[i] + blockSums[i >> 10];
        rowStart[i] = v;
        cursor[i]   = v;
    }
    if (i == n) rowStart[n] = nEdges;
}

__global__ __launch_bounds__(256) void fill_k(
    const int* __restrict__ src, const int* __restrict__ dst,
    int* __restrict__ cursor, int* __restrict__ eSrc, int nEdges)
{
    const int i = blockIdx.x * blockDim.x + threadIdx.x;
    if (i < nEdges) {
        const int pos = atomicAdd(&cursor[dst[i]], 1);
        eSrc[pos] = src[i];
    }
}

// ===========================================================================
// Gather aggregation (bf16): one wave per node, batched ILP (8/4/2/1).
// ===========================================================================
__global__ __launch_bounds__(256) void gather_agg_k(
    const unsigned short* __restrict__ feat,
    const int*            __restrict__ rowStart,
    const int*            __restrict__ eSrc,
    unsigned short*       __restrict__ agg,
    int nNodes)
{
    const int node = (int)((blockIdx.x * blockDim.x + threadIdx.x) >> 6);
    if (node >= nNodes) return;
    const int lane = threadIdx.x & 63;
    const int beg = rowStart[node];
    const int end = rowStart[node + 1];
    const size_t colOff = (size_t)lane * 2;

    float ax = 0.f, ay = 0.f;

    for (int base = beg; base < end; base += 64) {
        const int cnt = min(64, end - base);
        const int si = eSrc[base + min(lane, cnt - 1)];   // one load: 64 indices

        int j = 0;
        for (; j + 8 <= cnt; j += 8) {
            unsigned int v[8];
#pragma unroll
            for (int q = 0; q < 8; ++q) {
                const int s = __shfl(si, j + q, 64);
                v[q] = *reinterpret_cast<const unsigned int*>(feat + (size_t)s * HID + colOff);
            }
#pragma unroll
            for (int q = 0; q < 8; ++q) { ax += bf_lo(v[q]); ay += bf_hi(v[q]); }
        }
        if (j + 4 <= cnt) {
            unsigned int v[4];
#pragma unroll
            for (int q = 0; q < 4; ++q) {
                const int s = __shfl(si, j + q, 64);
                v[q] = *reinterpret_cast<const unsigned int*>(feat + (size_t)s * HID + colOff);
            }
#pragma unroll
            for (int q = 0; q < 4; ++q) { ax += bf_lo(v[q]); ay += bf_hi(v[q]); }
            j += 4;
        }
        if (j + 2 <= cnt) {
            const int s0 = __shfl(si, j, 64);
            const int s1 = __shfl(si, j + 1, 64);
            const unsigned int v0 = *reinterpret_cast<const unsigned int*>(feat + (size_t)s0 * HID + colOff);
            const unsigned int v1 = *reinterpret_cast<const unsigned int*>(feat + (size_t)s1 * HID + colOff);
            ax += bf_lo(v0) + bf_lo(v1);
            ay += bf_hi(v0) + bf_hi(v1);
            j += 2;
        }
        if (j < cnt) {
            const int s = __shfl(si, j, 64);
            const unsigned int v = *reinterpret_cast<const unsigned int*>(feat + (size_t)s * HID + colOff);
            ax += bf_lo(v);
            ay += bf_hi(v);
        }
    }

    const unsigned int packed = (unsigned int)f2bf(ax) | ((unsigned int)f2bf(ay) << 16);
    *reinterpret_cast<unsigned int*>(agg + (size_t)node * HID + colOff) = packed;
}

// ===========================================================================
// bf16 MFMA dual-GEMM, 2-phase double-buffered pipeline (T3-minimum):
// STAGE(t+1) issued before compute(t); raw s_barrier + counted vmcnt(8) so
// 8 global_load_lds per wave stay in flight across the barrier.
// ===========================================================================
__device__ __forceinline__ void stage_tile(
    const unsigned short* __restrict__ F, const unsigned short* __restrict__ Wm,
    unsigned short* XsBuf, unsigned short* WsBuf,
    int w, int stHalf, int rsub, int srcColB, int k0, int row0, int rowMax)
{
    if (w < 2) {
#pragma unroll
        for (int q = 0; q < 8; ++q) {
            const int row = stHalf * 64 + q * 8 + rsub;
            const int gr  = min(row0 + row, rowMax);
            gload16((const char*)(F + (size_t)gr * HID + k0) + srcColB,
                    XsBuf + (stHalf * 64 + q * 8) * 64);
        }
    } else {
#pragma unroll
        for (int q = 0; q < 8; ++q) {
            const int row = stHalf * 64 + q * 8 + rsub;
            gload16((const char*)(Wm + (size_t)row * HID + k0) + srcColB,
                    WsBuf + (stHalf * 64 + q * 8) * 64);
        }
    }
}

template <int MODE>
__global__ __launch_bounds__(256) void gemm_mfma_k(
    const unsigned short* __restrict__ X,
    const unsigned short* __restrict__ AGG,
    const unsigned short* __restrict__ Wroot,
    const unsigned short* __restrict__ Wrel,
    const float*          __restrict__ bias,
    void*                 __restrict__ OUTv,
    int nRows)
{
    __shared__ unsigned short Xs[2][128 * 64];
    __shared__ unsigned short Ws[2][128 * 64];

    const int tid  = threadIdx.x;
    const int lane = tid & 63;
    const int w    = tid >> 6;
    const int row0 = blockIdx.x * 128;

    const int wr = w >> 1, wc = w & 1;
    const int R0 = wr * 64, C0 = wc * 64;
    const int lr = lane & 15, lk = lane >> 4;
    const int swz = (lr & 7) << 4;           // read-side XOR (bytes)

    const int rsub    = lane >> 3;
    const int srcColB = (((lane & 7) ^ rsub) << 4);   // pre-swizzled src col (bytes)
    const int stHalf  = w & 1;
    const int rowMax  = nRows - 1;

    f32x4 acc[4][4];
#pragma unroll
    for (int m = 0; m < 4; ++m)
#pragma unroll
        for (int n = 0; n < 4; ++n) acc[m][n] = f32x4{0.f, 0.f, 0.f, 0.f};

    // phase t: t<2 -> (X,Wroot), t>=2 -> (AGG,Wrel); k0 = (t&1)*64
    stage_tile(X, Wroot, Xs[0], Ws[0], w, stHalf, rsub, srcColB, 0, row0, rowMax);

#pragma unroll
    for (int t = 0; t < 4; ++t) {
        const int cur = t & 1;
        if (t < 3) {
            const unsigned short* Fn = (t + 1 < 2) ? X : AGG;
            const unsigned short* Wn = (t + 1 < 2) ? Wroot : Wrel;
            stage_tile(Fn, Wn, Xs[cur ^ 1], Ws[cur ^ 1],
                       w, stHalf, rsub, srcColB, ((t + 1) & 1) * 64, row0, rowMax);
            asm volatile("s_waitcnt vmcnt(8)" ::: "memory");   // phase-t loads landed
        } else {
            asm volatile("s_waitcnt vmcnt(0)" ::: "memory");   // drain final phase
        }
        __builtin_amdgcn_s_barrier();

#pragma unroll
        for (int ks = 0; ks < 2; ++ks) {
            bf16x8 af[4], bfr[4];
            const int kB = (ks * 64 + lk * 16) ^ swz;
#pragma unroll
            for (int m = 0; m < 4; ++m) {
                const int row = R0 + m * 16 + lr;
                af[m] = *reinterpret_cast<const bf16x8*>((const char*)Xs[cur] + row * 128 + kB);
            }
#pragma unroll
            for (int n = 0; n < 4; ++n) {
                const int col = C0 + n * 16 + lr;
                bfr[n] = *reinterpret_cast<const bf16x8*>((const char*)Ws[cur] + col * 128 + kB);
            }
#pragma unroll
            for (int m = 0; m < 4; ++m)
#pragma unroll
                for (int n = 0; n < 4; ++n)
                    acc[m][n] = __builtin_amdgcn_mfma_f32_16x16x32_bf16(
                        af[m], bfr[n], acc[m][n], 0, 0, 0);
        }
        if (t < 3) __builtin_amdgcn_s_barrier();   // buffer free for restage
    }

    float bv[4];
#pragma unroll
    for (int n = 0; n < 4; ++n) bv[n] = bias[C0 + n * 16 + lr];

#pragma unroll
    for (int m = 0; m < 4; ++m) {
        const int rbase = row0 + R0 + m * 16 + lk * 4;
#pragma unroll
        for (int j = 0; j < 4; ++j) {
            const int r = rbase + j;
            if (r < nRows) {
#pragma unroll
                for (int n = 0; n < 4; ++n) {
                    const int col = C0 + n * 16 + lr;
                    float v = acc[m][n][j] + bv[n];
                    if (MODE == 0) {
                        v = fmaxf(v, 0.f);
                        ((unsigned short*)OUTv)[(size_t)r * HID + col] = f2bf(v);
                    } else {
                        ((float*)OUTv)[(size_t)r * HID + col] = v;
                    }
                }
            }
        }
    }
}

// ===========================================================================
extern "C" void kernel_launch(void* const* d_in, const int* in_sizes, int n_in,
                              void* d_out, int out_size, void* d_ws, size_t ws_size,
                              hipStream_t stream)
{
    const float* x      = (const float*)d_in[0];
    const int*   ei     = (const int*)  d_in[1];
    const float* Wrel0  = (const float*)d_in[2];
    const float* b0     = (const float*)d_in[3];
    const float* Wroot0 = (const float*)d_in[4];
    const float* Wrel1  = (const float*)d_in[5];
    const float* b1     = (const float*)d_in[6];
    const float* Wroot1 = (const float*)d_in[7];
    const float* Wrel2  = (const float*)d_in[8];
    const float* b2     = (const float*)d_in[9];
    const float* Wroot2 = (const float*)d_in[10];

    const int nNodes = in_sizes[0] / HID;   // 100000
    const int nEdges = in_sizes[1] / 2;     // 640000
    const int* srcI = ei;
    const int* dstI = ei + nEdges;
    const size_t nF = (size_t)nNodes * HID;

    float* OUT = (float*)d_out;

    // ---- workspace layout
    unsigned short* xb   = (unsigned short*)d_ws;
    unsigned short* hA   = xb + nF;
    unsigned short* hB   = hA + nF;
    unsigned short* aggb = hB + nF;
    unsigned short* wb   = aggb + nF;          // 6 x 128*128 bf16
    int* deg       = (int*)(wb + 6 * HID * HID);
    int* part      = deg + nNodes;
    int* rowStart  = part + nNodes;            // nNodes+1
    int* cursor    = rowStart + nNodes + 1;
    int* blockSums = cursor + nNodes;          // <=128
    int* eSrc      = blockSums + 128;          // nEdges

    unsigned short* Wrel0b  = wb + 0 * HID * HID;
    unsigned short* Wroot0b = wb + 1 * HID * HID;
    unsigned short* Wrel1b  = wb + 2 * HID * HID;
    unsigned short* Wroot1b = wb + 3 * HID * HID;
    unsigned short* Wrel2b  = wb + 4 * HID * HID;
    unsigned short* Wroot2b = wb + 5 * HID * HID;

    // ---- conversions
    cvt_x_k<<<(int)((nF / 4 + 255) / 256), 256, 0, stream>>>(x, xb, (int)(nF / 4));
    WPtrs wp;
    wp.s[0] = Wrel0;  wp.d[0] = Wrel0b;
    wp.s[1] = Wroot0; wp.d[1] = Wroot0b;
    wp.s[2] = Wrel1;  wp.d[2] = Wrel1b;
    wp.s[3] = Wroot1; wp.d[3] = Wroot1b;
    wp.s[4] = Wrel2;  wp.d[4] = Wrel2b;
    wp.s[5] = Wroot2; wp.d[5] = Wroot2b;
    cvt_w_k<<<dim3(16, 6), 256, 0, stream>>>(wp);

    // ---- build CSR by destination (once)
    const int nb = (nNodes + 1023) / 1024;
    hipMemsetAsync(deg, 0, (size_t)nNodes * sizeof(int), stream);
    hist_k<<<(nEdges + 255) / 256, 256, 0, stream>>>(dstI, deg, nEdges);
    scan1_k<<<nb, 256, 0, stream>>>(deg, part, blockSums, nNodes);
    scan2_k<<<1, 128, 0, stream>>>(blockSums, nb);
    scan3_k<<<(nNodes + 256) / 256, 256, 0, stream>>>(part, blockSums, rowStart, cursor, nNodes, nEdges);
    fill_k<<<(nEdges + 255) / 256, 256, 0, stream>>>(srcI, dstI, cursor, eSrc, nEdges);

    const int aGrid = (int)(((size_t)nNodes * 64 + 255) / 256);
    const int gGrid = (nNodes + 127) / 128;

    // ---- layer 0
    gather_agg_k<<<aGrid, 256, 0, stream>>>(xb, rowStart, eSrc, aggb, nNodes);
    gemm_mfma_k<0><<<gGrid, 256, 0, stream>>>(xb, aggb, Wroot0b, Wrel0b, b0, hA, nNodes);

    // ---- layer 1
    gather_agg_k<<<aGrid, 256, 0, stream>>>(hA, rowStart, eSrc, aggb, nNodes);
    gemm_mfma_k<0><<<gGrid, 256, 0, stream>>>(hA, aggb, Wroot1b, Wrel1b, b1, hB, nNodes);

    // ---- layer 2 (f32 out, no ReLU)
    gather_agg_k<<<aGrid, 256, 0, stream>>>(hB, rowStart, eSrc, aggb, nNodes);
    gemm_mfma_k<1><<<gGrid, 256, 0, stream>>>(hB, aggb, Wroot2b, Wrel2b, b2, OUT, nNodes);
}

// Round 7
// 206.808 us; speedup vs baseline: 9.2816x; 1.1808x over previous
//
#include <hip/hip_runtime.h>

constexpr int HID = 128;

typedef __attribute__((ext_vector_type(8))) short bf16x8;
typedef __attribute__((ext_vector_type(4))) float f32x4;

__device__ __forceinline__ unsigned short f2bf(float f) {
    unsigned int u = __float_as_uint(f);
    u += 0x7fffu + ((u >> 16) & 1u);            // RNE
    return (unsigned short)(u >> 16);
}
__device__ __forceinline__ float bf_lo(unsigned int v) { return __uint_as_float(v << 16); }
__device__ __forceinline__ float bf_hi(unsigned int v) { return __uint_as_float(v & 0xffff0000u); }

__device__ __forceinline__ void gload16(const void* g, void* l) {
    __builtin_amdgcn_global_load_lds(
        (const __attribute__((address_space(1))) void*)g,
        (__attribute__((address_space(3))) void*)l, 16, 0, 0);
}

// ===========================================================================
// f32 -> bf16 conversions
// ===========================================================================
__global__ __launch_bounds__(256) void cvt_x_k(
    const float* __restrict__ in, unsigned short* __restrict__ out, int n4)
{
    const int i = blockIdx.x * 256 + threadIdx.x;
    if (i >= n4) return;
    const float4 v = reinterpret_cast<const float4*>(in)[i];
    ushort4 o;
    o.x = f2bf(v.x); o.y = f2bf(v.y); o.z = f2bf(v.z); o.w = f2bf(v.w);
    reinterpret_cast<ushort4*>(out)[i] = o;
}

struct WPtrs { const float* s[6]; unsigned short* d[6]; };
__global__ __launch_bounds__(256) void cvt_w_k(WPtrs p)
{
    const int which = blockIdx.y;
    const int i = blockIdx.x * 256 + threadIdx.x;
    if (i >= (HID * HID) / 4) return;
    const float4 v = reinterpret_cast<const float4*>(p.s[which])[i];
    ushort4 o;
    o.x = f2bf(v.x); o.y = f2bf(v.y); o.z = f2bf(v.z); o.w = f2bf(v.w);
    reinterpret_cast<ushort4*>(p.d[which])[i] = o;
}

// ===========================================================================
// CSR-by-dst construction (once per launch). One atomic pass:
// hist_rank_k: deg histogram + per-edge rank (atomic return value).
// fill2_k:     eSrc[rowStart[dst] + rank] = src   (no atomics).
// ===========================================================================
__global__ __launch_bounds__(256) void hist_rank_k(
    const int* __restrict__ dst, int* __restrict__ deg,
    int* __restrict__ rank, int nEdges)
{
    const int i = blockIdx.x * blockDim.x + threadIdx.x;
    if (i < nEdges) rank[i] = atomicAdd(&deg[dst[i]], 1);
}

__global__ __launch_bounds__(256) void scan1_k(
    const int* __restrict__ deg, int* __restrict__ part,
    int* __restrict__ blockSums, int n)
{
    __shared__ int s[256];
    const int t = threadIdx.x;
    const int i = blockIdx.x * 1024 + t * 4;
    const int e0 = (i + 0 < n) ? deg[i + 0] : 0;
    const int e1 = (i + 1 < n) ? deg[i + 1] : 0;
    const int e2 = (i + 2 < n) ? deg[i + 2] : 0;
    const int e3 = (i + 3 < n) ? deg[i + 3] : 0;
    const int local = e0 + e1 + e2 + e3;
    s[t] = local;
    __syncthreads();
    for (int off = 1; off < 256; off <<= 1) {
        int v = 0;
        if (t >= off) v = s[t - off];
        __syncthreads();
        if (t >= off) s[t] += v;
        __syncthreads();
    }
    const int incl = s[t];
    int excl = incl - local;
    if (t == 255) blockSums[blockIdx.x] = incl;
    if (i + 0 < n) part[i + 0] = excl; excl += e0;
    if (i + 1 < n) part[i + 1] = excl; excl += e1;
    if (i + 2 < n) part[i + 2] = excl; excl += e2;
    if (i + 3 < n) part[i + 3] = excl;
}

__global__ __launch_bounds__(128) void scan2_k(int* __restrict__ blockSums, int nb)
{
    __shared__ int s[128];
    const int t = threadIdx.x;
    const int v = (t < nb) ? blockSums[t] : 0;
    s[t] = v;
    __syncthreads();
    for (int off = 1; off < 128; off <<= 1) {
        int u = 0;
        if (t >= off) u = s[t - off];
        __syncthreads();
        if (t >= off) s[t] += u;
        __syncthreads();
    }
    if (t < nb) blockSums[t] = s[t] - v;   // exclusive
}

__global__ __launch_bounds__(256) void scan3_k(
    const int* __restrict__ part, const int* __restrict__ blockSums,
    int* __restrict__ rowStart, int n, int nEdges)
{
    const int i = blockIdx.x * blockDim.x + threadIdx.x;
    if (i < n) rowStart[i] = part[i] + blockSums[i >> 10];
    if (i == n) rowStart[n] = nEdges;
}

__global__ __launch_bounds__(256) void fill2_k(
    const int* __restrict__ src, const int* __restrict__ dst,
    const int* __restrict__ rank, const int* __restrict__ rowStart,
    int* __restrict__ eSrc, int nEdges)
{
    const int i = blockIdx.x * blockDim.x + threadIdx.x;
    if (i < nEdges) eSrc[rowStart[dst[i]] + rank[i]] = src[i];
}

// ===========================================================================
// Gather aggregation (bf16): 4 nodes per wave, 16 lanes per node,
// uint4 (8 bf16) per lane. Each load instruction carries 4 edges ->
// 4x in-flight bytes per wave vs the 64-lane-per-node version.
// ===========================================================================
__global__ __launch_bounds__(256) void gather_agg_k(
    const unsigned short* __restrict__ feat,
    const int*            __restrict__ rowStart,
    const int*            __restrict__ eSrc,
    unsigned short*       __restrict__ agg,
    int nNodes)
{
    const int wid  = (blockIdx.x * blockDim.x + threadIdx.x) >> 6;
    const int lane = threadIdx.x & 63;
    const int g    = lane >> 4;        // subgroup 0..3
    const int sl   = lane & 15;        // lane within subgroup
    const int node = wid * 4 + g;
    if (node >= nNodes) return;

    const int beg = rowStart[node];
    const int end = rowStart[node + 1];
    const size_t colOff = (size_t)sl * 8;      // elements (16B)
    const int gbase = g << 4;

    float acc[8];
#pragma unroll
    for (int q = 0; q < 8; ++q) acc[q] = 0.f;

    for (int base = beg; base < end; base += 16) {
        const int cnt = min(16, end - base);
        const int si = eSrc[base + min(sl, cnt - 1)];   // 16 indices per subgroup

        int j = 0;
        for (; j + 8 <= cnt; j += 8) {
            uint4 v[8];
#pragma unroll
            for (int q = 0; q < 8; ++q) {
                const int s = __shfl(si, gbase + j + q, 64);
                v[q] = *reinterpret_cast<const uint4*>(feat + (size_t)s * HID + colOff);
            }
#pragma unroll
            for (int q = 0; q < 8; ++q) {
                acc[0] += bf_lo(v[q].x); acc[1] += bf_hi(v[q].x);
                acc[2] += bf_lo(v[q].y); acc[3] += bf_hi(v[q].y);
                acc[4] += bf_lo(v[q].z); acc[5] += bf_hi(v[q].z);
                acc[6] += bf_lo(v[q].w); acc[7] += bf_hi(v[q].w);
            }
        }
        if (j + 4 <= cnt) {
            uint4 v[4];
#pragma unroll
            for (int q = 0; q < 4; ++q) {
                const int s = __shfl(si, gbase + j + q, 64);
                v[q] = *reinterpret_cast<const uint4*>(feat + (size_t)s * HID + colOff);
            }
#pragma unroll
            for (int q = 0; q < 4; ++q) {
                acc[0] += bf_lo(v[q].x); acc[1] += bf_hi(v[q].x);
                acc[2] += bf_lo(v[q].y); acc[3] += bf_hi(v[q].y);
                acc[4] += bf_lo(v[q].z); acc[5] += bf_hi(v[q].z);
                acc[6] += bf_lo(v[q].w); acc[7] += bf_hi(v[q].w);
            }
            j += 4;
        }
        if (j + 2 <= cnt) {
            uint4 v[2];
#pragma unroll
            for (int q = 0; q < 2; ++q) {
                const int s = __shfl(si, gbase + j + q, 64);
                v[q] = *reinterpret_cast<const uint4*>(feat + (size_t)s * HID + colOff);
            }
#pragma unroll
            for (int q = 0; q < 2; ++q) {
                acc[0] += bf_lo(v[q].x); acc[1] += bf_hi(v[q].x);
                acc[2] += bf_lo(v[q].y); acc[3] += bf_hi(v[q].y);
                acc[4] += bf_lo(v[q].z); acc[5] += bf_hi(v[q].z);
                acc[6] += bf_lo(v[q].w); acc[7] += bf_hi(v[q].w);
            }
            j += 2;
        }
        if (j < cnt) {
            const int s = __shfl(si, gbase + j, 64);
            const uint4 v = *reinterpret_cast<const uint4*>(feat + (size_t)s * HID + colOff);
            acc[0] += bf_lo(v.x); acc[1] += bf_hi(v.x);
            acc[2] += bf_lo(v.y); acc[3] += bf_hi(v.y);
            acc[4] += bf_lo(v.z); acc[5] += bf_hi(v.z);
            acc[6] += bf_lo(v.w); acc[7] += bf_hi(v.w);
        }
    }

    uint4 o;
    o.x = (unsigned int)f2bf(acc[0]) | ((unsigned int)f2bf(acc[1]) << 16);
    o.y = (unsigned int)f2bf(acc[2]) | ((unsigned int)f2bf(acc[3]) << 16);
    o.z = (unsigned int)f2bf(acc[4]) | ((unsigned int)f2bf(acc[5]) << 16);
    o.w = (unsigned int)f2bf(acc[6]) | ((unsigned int)f2bf(acc[7]) << 16);
    *reinterpret_cast<uint4*>(agg + (size_t)node * HID + colOff) = o;
}

// ===========================================================================
// bf16 MFMA dual-GEMM, 2-phase double-buffered pipeline (unchanged).
// ===========================================================================
__device__ __forceinline__ void stage_tile(
    const unsigned short* __restrict__ F, const unsigned short* __restrict__ Wm,
    unsigned short* XsBuf, unsigned short* WsBuf,
    int w, int stHalf, int rsub, int srcColB, int k0, int row0, int rowMax)
{
    if (w < 2) {
#pragma unroll
        for (int q = 0; q < 8; ++q) {
            const int row = stHalf * 64 + q * 8 + rsub;
            const int gr  = min(row0 + row, rowMax);
            gload16((const char*)(F + (size_t)gr * HID + k0) + srcColB,
                    XsBuf + (stHalf * 64 + q * 8) * 64);
        }
    } else {
#pragma unroll
        for (int q = 0; q < 8; ++q) {
            const int row = stHalf * 64 + q * 8 + rsub;
            gload16((const char*)(Wm + (size_t)row * HID + k0) + srcColB,
                    WsBuf + (stHalf * 64 + q * 8) * 64);
        }
    }
}

template <int MODE>
__global__ __launch_bounds__(256) void gemm_mfma_k(
    const unsigned short* __restrict__ X,
    const unsigned short* __restrict__ AGG,
    const unsigned short* __restrict__ Wroot,
    const unsigned short* __restrict__ Wrel,
    const float*          __restrict__ bias,
    void*                 __restrict__ OUTv,
    int nRows)
{
    __shared__ unsigned short Xs[2][128 * 64];
    __shared__ unsigned short Ws[2][128 * 64];

    const int tid  = threadIdx.x;
    const int lane = tid & 63;
    const int w    = tid >> 6;
    const int row0 = blockIdx.x * 128;

    const int wr = w >> 1, wc = w & 1;
    const int R0 = wr * 64, C0 = wc * 64;
    const int lr = lane & 15, lk = lane >> 4;
    const int swz = (lr & 7) << 4;

    const int rsub    = lane >> 3;
    const int srcColB = (((lane & 7) ^ rsub) << 4);
    const int stHalf  = w & 1;
    const int rowMax  = nRows - 1;

    f32x4 acc[4][4];
#pragma unroll
    for (int m = 0; m < 4; ++m)
#pragma unroll
        for (int n = 0; n < 4; ++n) acc[m][n] = f32x4{0.f, 0.f, 0.f, 0.f};

    stage_tile(X, Wroot, Xs[0], Ws[0], w, stHalf, rsub, srcColB, 0, row0, rowMax);

#pragma unroll
    for (int t = 0; t < 4; ++t) {
        const int cur = t & 1;
        if (t < 3) {
            const unsigned short* Fn = (t + 1 < 2) ? X : AGG;
            const unsigned short* Wn = (t + 1 < 2) ? Wroot : Wrel;
            stage_tile(Fn, Wn, Xs[cur ^ 1], Ws[cur ^ 1],
                       w, stHalf, rsub, srcColB, ((t + 1) & 1) * 64, row0, rowMax);
            asm volatile("s_waitcnt vmcnt(8)" ::: "memory");
        } else {
            asm volatile("s_waitcnt vmcnt(0)" ::: "memory");
        }
        __builtin_amdgcn_s_barrier();

#pragma unroll
        for (int ks = 0; ks < 2; ++ks) {
            bf16x8 af[4], bfr[4];
            const int kB = (ks * 64 + lk * 16) ^ swz;
#pragma unroll
            for (int m = 0; m < 4; ++m) {
                const int row = R0 + m * 16 + lr;
                af[m] = *reinterpret_cast<const bf16x8*>((const char*)Xs[cur] + row * 128 + kB);
            }
#pragma unroll
            for (int n = 0; n < 4; ++n) {
                const int col = C0 + n * 16 + lr;
                bfr[n] = *reinterpret_cast<const bf16x8*>((const char*)Ws[cur] + col * 128 + kB);
            }
#pragma unroll
            for (int m = 0; m < 4; ++m)
#pragma unroll
                for (int n = 0; n < 4; ++n)
                    acc[m][n] = __builtin_amdgcn_mfma_f32_16x16x32_bf16(
                        af[m], bfr[n], acc[m][n], 0, 0, 0);
        }
        if (t < 3) __builtin_amdgcn_s_barrier();
    }

    float bv[4];
#pragma unroll
    for (int n = 0; n < 4; ++n) bv[n] = bias[C0 + n * 16 + lr];

#pragma unroll
    for (int m = 0; m < 4; ++m) {
        const int rbase = row0 + R0 + m * 16 + lk * 4;
#pragma unroll
        for (int j = 0; j < 4; ++j) {
            const int r = rbase + j;
            if (r < nRows) {
#pragma unroll
                for (int n = 0; n < 4; ++n) {
                    const int col = C0 + n * 16 + lr;
                    float v = acc[m][n][j] + bv[n];
                    if (MODE == 0) {
                        v = fmaxf(v, 0.f);
                        ((unsigned short*)OUTv)[(size_t)r * HID + col] = f2bf(v);
                    } else {
                        ((float*)OUTv)[(size_t)r * HID + col] = v;
                    }
                }
            }
        }
    }
}

// ===========================================================================
extern "C" void kernel_launch(void* const* d_in, const int* in_sizes, int n_in,
                              void* d_out, int out_size, void* d_ws, size_t ws_size,
                              hipStream_t stream)
{
    const float* x      = (const float*)d_in[0];
    const int*   ei     = (const int*)  d_in[1];
    const float* Wrel0  = (const float*)d_in[2];
    const float* b0     = (const float*)d_in[3];
    const float* Wroot0 = (const float*)d_in[4];
    const float* Wrel1  = (const float*)d_in[5];
    const float* b1     = (const float*)d_in[6];
    const float* Wroot1 = (const float*)d_in[7];
    const float* Wrel2  = (const float*)d_in[8];
    const float* b2     = (const float*)d_in[9];
    const float* Wroot2 = (const float*)d_in[10];

    const int nNodes = in_sizes[0] / HID;   // 100000
    const int nEdges = in_sizes[1] / 2;     // 640000
    const int* srcI = ei;
    const int* dstI = ei + nEdges;
    const size_t nF = (size_t)nNodes * HID;

    float* OUT = (float*)d_out;

    // ---- workspace layout
    unsigned short* xb   = (unsigned short*)d_ws;
    unsigned short* hA   = xb + nF;
    unsigned short* hB   = hA + nF;
    unsigned short* aggb = hB + nF;
    unsigned short* wb   = aggb + nF;          // 6 x 128*128 bf16
    int* deg       = (int*)(wb + 6 * HID * HID);
    int* part      = deg + nNodes;
    int* rowStart  = part + nNodes;            // nNodes+1
    int* blockSums = rowStart + nNodes + 1;    // <=128
    int* rank      = blockSums + 128;          // nEdges
    int* eSrc      = rank + nEdges;            // nEdges

    unsigned short* Wrel0b  = wb + 0 * HID * HID;
    unsigned short* Wroot0b = wb + 1 * HID * HID;
    unsigned short* Wrel1b  = wb + 2 * HID * HID;
    unsigned short* Wroot1b = wb + 3 * HID * HID;
    unsigned short* Wrel2b  = wb + 4 * HID * HID;
    unsigned short* Wroot2b = wb + 5 * HID * HID;

    // ---- conversions
    cvt_x_k<<<(int)((nF / 4 + 255) / 256), 256, 0, stream>>>(x, xb, (int)(nF / 4));
    WPtrs wp;
    wp.s[0] = Wrel0;  wp.d[0] = Wrel0b;
    wp.s[1] = Wroot0; wp.d[1] = Wroot0b;
    wp.s[2] = Wrel1;  wp.d[2] = Wrel1b;
    wp.s[3] = Wroot1; wp.d[3] = Wroot1b;
    wp.s[4] = Wrel2;  wp.d[4] = Wrel2b;
    wp.s[5] = Wroot2; wp.d[5] = Wroot2b;
    cvt_w_k<<<dim3(16, 6), 256, 0, stream>>>(wp);

    // ---- build CSR by destination (one atomic pass)
    const int nb = (nNodes + 1023) / 1024;
    hipMemsetAsync(deg, 0, (size_t)nNodes * sizeof(int), stream);
    hist_rank_k<<<(nEdges + 255) / 256, 256, 0, stream>>>(dstI, deg, rank, nEdges);
    scan1_k<<<nb, 256, 0, stream>>>(deg, part, blockSums, nNodes);
    scan2_k<<<1, 128, 0, stream>>>(blockSums, nb);
    scan3_k<<<(nNodes + 256) / 256, 256, 0, stream>>>(part, blockSums, rowStart, nNodes, nEdges);
    fill2_k<<<(nEdges + 255) / 256, 256, 0, stream>>>(srcI, dstI, rank, rowStart, eSrc, nEdges);

    const int aGrid = (int)(((size_t)(nNodes + 3) / 4 * 64 + 255) / 256);  // 4 nodes/wave
    const int gGrid = (nNodes + 127) / 128;

    // ---- layer 0
    gather_agg_k<<<aGrid, 256, 0, stream>>>(xb, rowStart, eSrc, aggb, nNodes);
    gemm_mfma_k<0><<<gGrid, 256, 0, stream>>>(xb, aggb, Wroot0b, Wrel0b, b0, hA, nNodes);

    // ---- layer 1
    gather_agg_k<<<aGrid, 256, 0, stream>>>(hA, rowStart, eSrc, aggb, nNodes);
    gemm_mfma_k<0><<<gGrid, 256, 0, stream>>>(hA, aggb, Wroot1b, Wrel1b, b1, hB, nNodes);

    // ---- layer 2 (f32 out, no ReLU)
    gather_agg_k<<<aGrid, 256, 0, stream>>>(hB, rowStart, eSrc, aggb, nNodes);
    gemm_mfma_k<1><<<gGrid, 256, 0, stream>>>(hB, aggb, Wroot2b, Wrel2b, b2, OUT, nNodes);
}